// Round 8
// baseline (543.039 us; speedup 1.0000x reference)
//
#include <hip/hip_runtime.h>
#include <hip/hip_bf16.h>
#include <cstdint>
#include <cstddef>

#define B_ 4
#define N_ 10000
#define E_ 160000
#define H_ 128
#define HEADS_ 4
#define HH_ 512
#define NROWS (B_*N_)

typedef __attribute__((ext_vector_type(8))) short bf16x8;
typedef __attribute__((ext_vector_type(4))) float f32x4;
typedef __attribute__((ext_vector_type(2))) float f32x2;

__device__ __forceinline__ float lrelu(float x){ return x > 0.f ? x : 0.2f*x; }
__device__ __forceinline__ unsigned short f2b(float f){
  unsigned int u = __builtin_bit_cast(unsigned int, f);
  unsigned int r = (u + 0x7fffu + ((u >> 16) & 1u)) >> 16;
  return (unsigned short)r;
}
__device__ __forceinline__ float blo(unsigned int u){ return __builtin_bit_cast(float, u << 16); }
__device__ __forceinline__ float bhi(unsigned int u){ return __builtin_bit_cast(float, u & 0xffff0000u); }

__device__ __forceinline__ void acc_row(f32x2* ac, float al, uint4 h){
  f32x2 v = {al, al};
  ac[0] += v * (f32x2){blo(h.x), bhi(h.x)};
  ac[1] += v * (f32x2){blo(h.y), bhi(h.y)};
  ac[2] += v * (f32x2){blo(h.z), bhi(h.z)};
  ac[3] += v * (f32x2){blo(h.w), bhi(h.w)};
}

// ---------------- CSR build ----------------
__global__ void k_count(const int* __restrict__ tgt, int* __restrict__ cnt){
  int e = blockIdx.x*blockDim.x + threadIdx.x;
  int b = blockIdx.y;
  int t = tgt[(size_t)b*E_ + e];
  atomicAdd(&cnt[b*N_ + t], 1);
}

__global__ void k_scan(const int* __restrict__ cnt, int* __restrict__ off, int* __restrict__ cursor){
  int b = blockIdx.x;
  __shared__ int wsum[16];
  __shared__ int carry_s;
  int lane = threadIdx.x & 63, wid = threadIdx.x >> 6;
  if (threadIdx.x == 0){ carry_s = 0; off[b*(N_+1)] = 0; }
  __syncthreads();
  for (int base = 0; base < N_; base += 1024){
    int i = base + threadIdx.x;
    int v = (i < N_) ? cnt[b*N_ + i] : 0;
    int x = v;
    #pragma unroll
    for (int d = 1; d < 64; d <<= 1){
      int y = __shfl_up(x, d);
      if (lane >= d) x += y;
    }
    if (lane == 63) wsum[wid] = x;
    __syncthreads();
    if (wid == 0 && lane < 16){
      int w = wsum[lane];
      #pragma unroll
      for (int d = 1; d < 16; d <<= 1){
        int y = __shfl_up(w, d, 16);
        if (lane >= d) w += y;
      }
      wsum[lane] = w;
    }
    __syncthreads();
    int excl = (wid ? wsum[wid-1] : 0) + carry_s;
    if (i < N_){
      int inc = x + excl;
      off[b*(N_+1) + i + 1] = inc;
      cursor[b*N_ + i] = inc - v;
    }
    __syncthreads();
    if (threadIdx.x == 0) carry_s += wsum[15];
    __syncthreads();
  }
}

__global__ void k_scatter(const int* __restrict__ src, const int* __restrict__ tgt,
                          int* __restrict__ cursor, int* __restrict__ csr){
  int e = blockIdx.x*blockDim.x + threadIdx.x;
  int b = blockIdx.y;
  int t = tgt[(size_t)b*E_ + e];
  int pos = atomicAdd(&cursor[b*N_ + t], 1);
  csr[(size_t)b*E_ + pos] = src[(size_t)b*E_ + e];
}

// ---------------- prep: Wa tables + W transpose/cast, all 3 layers ----------------
__global__ void k_prep(const float* __restrict__ W0, const float* __restrict__ W1, const float* __restrict__ W2,
                       const float* __restrict__ as0, const float* __restrict__ as1, const float* __restrict__ as2,
                       const float* __restrict__ ad0, const float* __restrict__ ad1, const float* __restrict__ ad2,
                       float* __restrict__ wasA, float* __restrict__ wadA, unsigned short* __restrict__ wtA){
  int l = blockIdx.y;
  const float* W   = (l==0)?W0:(l==1)?W1:W2;
  const float* asp = (l==0)?as0:(l==1)?as1:as2;
  const float* adp = (l==0)?ad0:(l==1)?ad1:ad2;
  if (blockIdx.x < 256){
    int i = blockIdx.x*256 + threadIdx.x;     // i = c*H_ + k
    int c = i >> 7, k = i & 127;
    wtA[(size_t)l*HH_*H_ + i] = f2b(W[(size_t)k*HH_ + c]);
  } else {
    int j = (blockIdx.x - 256)*256 + threadIdx.x;   // j = k*4 + h
    if (j < H_*HEADS_){
      int k = j >> 2, h = j & 3;
      const float* wrow = W + (size_t)k*HH_ + h*H_;
      const float* asr = asp + h*H_;
      const float* adr = adp + h*H_;
      float ss = 0.f, sd = 0.f;
      for (int c = 0; c < H_; ++c){ float w = wrow[c]; ss += w*asr[c]; sd += w*adr[c]; }
      wasA[l*HH_ + j] = ss; wadA[l*HH_ + j] = sd;
    }
  }
}

// ---------------- layer-1: cast x->bf16 + logits (one wave per row) ----------------
__global__ __launch_bounds__(256) void k_cast_logits(const float* __restrict__ X,
    const float* __restrict__ was, const float* __restrict__ wad,
    unsigned short* __restrict__ Xb, float* __restrict__ es, float* __restrict__ ed){
  int gw = (blockIdx.x*blockDim.x + threadIdx.x) >> 6;
  int lane = threadIdx.x & 63;
  float2 v = *(const float2*)(X + (size_t)gw*H_ + lane*2);
  unsigned int o = ((unsigned int)f2b(v.y) << 16) | (unsigned int)f2b(v.x);
  *(unsigned int*)(Xb + (size_t)gw*H_ + lane*2) = o;
  int c = lane*2;
  const f32x4* w4 = (const f32x4*)was;
  const f32x4* d4 = (const f32x4*)wad;
  f32x4 se = v.x*w4[c] + v.y*w4[c+1];
  f32x4 de = v.x*d4[c] + v.y*d4[c+1];
  #pragma unroll
  for (int d = 1; d < 64; d <<= 1){
    se.x += __shfl_xor(se.x,d); se.y += __shfl_xor(se.y,d);
    se.z += __shfl_xor(se.z,d); se.w += __shfl_xor(se.w,d);
    de.x += __shfl_xor(de.x,d); de.y += __shfl_xor(de.y,d);
    de.z += __shfl_xor(de.z,d); de.w += __shfl_xor(de.w,d);
  }
  if (lane == 0){
    *(float4*)(es + (size_t)gw*4) = make_float4(se.x, se.y, se.z, se.w);
    *(float4*)(ed + (size_t)gw*4) = make_float4(de.x, de.y, de.z, de.w);
  }
}

// ---------------- h = x @ W  (bf16 MFMA 16x16x32; 64x64 tile) ----------------
__global__ __launch_bounds__(256) void k_gemm_mfma(const unsigned short* __restrict__ Xb,
    const unsigned short* __restrict__ Wt, unsigned short* __restrict__ Hb){
  __shared__ unsigned short xs[64*128];
  __shared__ unsigned short ws[64*128];
  int row0 = blockIdx.x * 64, col0 = blockIdx.y * 64;
  int tid = threadIdx.x;
  int ch = tid & 15, r0 = tid >> 4;
  #pragma unroll
  for (int p = 0; p < 4; ++p){
    int r = r0 + p*16;
    int sc = ch ^ (r & 7);
    *(uint4*)(&xs[r*128 + sc*8]) = *(const uint4*)(Xb + (size_t)(row0 + r)*H_ + ch*8);
    *(uint4*)(&ws[r*128 + sc*8]) = *(const uint4*)(Wt + (size_t)(col0 + r)*H_ + ch*8);
  }
  __syncthreads();
  int w = tid >> 6, l = tid & 63;
  int lr = l & 15, q = l >> 4;
  f32x4 z = {0.f, 0.f, 0.f, 0.f};
  f32x4 acc[4] = {z, z, z, z};
  int arow = w*16 + lr;
  #pragma unroll
  for (int kf = 0; kf < 4; ++kf){
    int bch = kf*4 + q;
    bf16x8 a = *(const bf16x8*)(&xs[arow*128 + (bch ^ (arow & 7))*8]);
    #pragma unroll
    for (int cf = 0; cf < 4; ++cf){
      int brow = cf*16 + lr;
      bf16x8 bfr = *(const bf16x8*)(&ws[brow*128 + (bch ^ (brow & 7))*8]);
      acc[cf] = __builtin_amdgcn_mfma_f32_16x16x32_bf16(a, bfr, acc[cf], 0, 0, 0);
    }
  }
  #pragma unroll
  for (int cf = 0; cf < 4; ++cf){
    #pragma unroll
    for (int rg = 0; rg < 4; ++rg){
      int row = row0 + w*16 + q*4 + rg;
      int col = col0 + cf*16 + lr;
      Hb[(size_t)row*HH_ + col] = f2b(acc[cf][rg]);
    }
  }
}

// ---- aggregate: 2 waves per node (even/odd edge split) + fused epilogue ----
template<bool FINAL>
__global__ __launch_bounds__(256) void k_aggregate(
    const unsigned short* __restrict__ Hb,
    const float* __restrict__ es, const float* __restrict__ ed,
    const int* __restrict__ off, const int* __restrict__ csr,
    const float* __restrict__ bias,
    const float* __restrict__ wasN, const float* __restrict__ wadN,
    const float* __restrict__ lng, const float* __restrict__ lnb,
    float* __restrict__ Yout, unsigned short* __restrict__ Xbout,
    float* __restrict__ esN, float* __restrict__ edN)
{
  __shared__ float part_s[2][16][8];   // wave1 partials per node
  __shared__ float orow_s[2][128];
  int wv = threadIdx.x >> 6, lane = threadIdx.x & 63;
  int nd = wv >> 1;                    // node within block (0/1)
  int pw = wv & 1;                     // wave within node pair (0/1)
  int gw = blockIdx.x*2 + nd;
  int b = gw / N_, t = gw - b*N_;
  const float4 edv = *(const float4*)(ed + (size_t)gw*4);
  int start = off[b*(N_+1) + t];
  int deg = off[b*(N_+1) + t + 1] - start;
  int total = deg + 1;                 // + implicit self-loop
  const int* lst = csr + (size_t)b*E_ + start;
  const float* esb = es + (size_t)b*N_*4;
  int head = lane >> 4;
  int cb = head*H_ + (lane & 15)*8;
  const unsigned short* hbase = Hb + (size_t)b*N_*HH_;
  float edh = head==0 ? edv.x : head==1 ? edv.y : head==2 ? edv.z : edv.w;
  float Mh, rSh;

  if (total <= 64){
    // ---- exact softmax stats, lane-per-edge (identical in both waves) ----
    bool valid = lane < total;
    int srcn = (lane < deg) ? lst[lane] : t;
    float4 ev = *(const float4*)(esb + (size_t)srcn*4);
    float e0 = valid ? lrelu(ev.x + edv.x) : -1e30f;
    float e1 = valid ? lrelu(ev.y + edv.y) : -1e30f;
    float e2 = valid ? lrelu(ev.z + edv.z) : -1e30f;
    float e3 = valid ? lrelu(ev.w + edv.w) : -1e30f;
    float M0 = e0, M1 = e1, M2 = e2, M3 = e3;
    #pragma unroll
    for (int d = 1; d < 64; d <<= 1){
      M0 = fmaxf(M0, __shfl_xor(M0, d)); M1 = fmaxf(M1, __shfl_xor(M1, d));
      M2 = fmaxf(M2, __shfl_xor(M2, d)); M3 = fmaxf(M3, __shfl_xor(M3, d));
    }
    float p0 = valid ? __expf(e0 - M0) : 0.f;
    float p1 = valid ? __expf(e1 - M1) : 0.f;
    float p2 = valid ? __expf(e2 - M2) : 0.f;
    float p3 = valid ? __expf(e3 - M3) : 0.f;
    float S0 = p0, S1 = p1, S2 = p2, S3 = p3;
    #pragma unroll
    for (int d = 1; d < 64; d <<= 1){
      S0 += __shfl_xor(S0, d); S1 += __shfl_xor(S1, d);
      S2 += __shfl_xor(S2, d); S3 += __shfl_xor(S3, d);
    }
    Mh = head==0 ? M0 : head==1 ? M1 : head==2 ? M2 : M3;
    float Sh = head==0 ? S0 : head==1 ? S1 : head==2 ? S2 : S3;
    rSh = 1.0f / Sh;
  } else {
    // ---- slow path: online softmax over all edges (identical in both waves) ----
    float m0=-1e30f, m1=-1e30f, m2=-1e30f, m3=-1e30f;
    float s0=0.f, s1=0.f, s2=0.f, s3=0.f;
    for (int i2 = lane; i2 <= deg; i2 += 64){
      int srcn = (i2 < deg) ? lst[i2] : t;
      float4 ev = *(const float4*)(esb + (size_t)srcn*4);
      float e0 = lrelu(ev.x + edv.x);
      float e1 = lrelu(ev.y + edv.y);
      float e2 = lrelu(ev.z + edv.z);
      float e3 = lrelu(ev.w + edv.w);
      float nm;
      nm = fmaxf(m0, e0); s0 = s0*__expf(m0-nm) + __expf(e0-nm); m0 = nm;
      nm = fmaxf(m1, e1); s1 = s1*__expf(m1-nm) + __expf(e1-nm); m1 = nm;
      nm = fmaxf(m2, e2); s2 = s2*__expf(m2-nm) + __expf(e2-nm); m2 = nm;
      nm = fmaxf(m3, e3); s3 = s3*__expf(m3-nm) + __expf(e3-nm); m3 = nm;
    }
    #pragma unroll
    for (int d = 1; d < 64; d <<= 1){
      float om, os, nm;
      om = __shfl_xor(m0, d); os = __shfl_xor(s0, d); nm = fmaxf(m0, om);
      s0 = s0*__expf(m0-nm) + os*__expf(om-nm); m0 = nm;
      om = __shfl_xor(m1, d); os = __shfl_xor(s1, d); nm = fmaxf(m1, om);
      s1 = s1*__expf(m1-nm) + os*__expf(om-nm); m1 = nm;
      om = __shfl_xor(m2, d); os = __shfl_xor(s2, d); nm = fmaxf(m2, om);
      s2 = s2*__expf(m2-nm) + os*__expf(om-nm); m2 = nm;
      om = __shfl_xor(m3, d); os = __shfl_xor(s3, d); nm = fmaxf(m3, om);
      s3 = s3*__expf(m3-nm) + os*__expf(om-nm); m3 = nm;
    }
    Mh = head==0 ? m0 : head==1 ? m1 : head==2 ? m2 : m3;
    float Sh = head==0 ? s0 : head==1 ? s1 : head==2 ? s2 : s3;
    rSh = 1.0f / Sh;
  }

  // ---- phase B: this wave handles edges pw, pw+2, ... (R2-proven loop shape) ----
  f32x2 zz = {0.f, 0.f};
  f32x2 ac[4] = {zz, zz, zz, zz};
  int i = pw;
  for (; i + 2 < total; i += 4){
    int sA = lst[i];                         // i < deg guaranteed here
    int sB = (i + 2 < deg) ? lst[i+2] : t;
    float eA = esb[(size_t)sA*4 + head];
    float eB = esb[(size_t)sB*4 + head];
    uint4 hA = *(const uint4*)(hbase + (size_t)sA*HH_ + cb);
    uint4 hB = *(const uint4*)(hbase + (size_t)sB*HH_ + cb);
    float aA = __expf(lrelu(eA + edh) - Mh) * rSh;
    float aB = __expf(lrelu(eB + edh) - Mh) * rSh;
    acc_row(ac, aA, hA);
    acc_row(ac, aB, hB);
  }
  if (i < total){
    int sA = (i < deg) ? lst[i] : t;
    float eA = esb[(size_t)sA*4 + head];
    uint4 hA = *(const uint4*)(hbase + (size_t)sA*HH_ + cb);
    float aA = __expf(lrelu(eA + edh) - Mh) * rSh;
    acc_row(ac, aA, hA);
  }

  // ---- head mean within wave ----
  float a[8] = {ac[0].x, ac[0].y, ac[1].x, ac[1].y, ac[2].x, ac[2].y, ac[3].x, ac[3].y};
  #pragma unroll
  for (int d = 16; d < 64; d <<= 1)
    #pragma unroll
    for (int j = 0; j < 8; j++) a[j] += __shfl_xor(a[j], d);

  // ---- cross-wave combine ----
  if (pw == 1 && lane < 16){
    #pragma unroll
    for (int j = 0; j < 8; j++) part_s[nd][lane][j] = a[j];
  }
  __syncthreads();

  int c = (lane & 15)*8;
  if (pw == 0){
    float tot[8];
    if (lane < 16){
      #pragma unroll
      for (int j = 0; j < 8; j++) tot[j] = a[j] + part_s[nd][lane][j];
    }
    if (FINAL){
      if (lane < 16){
        float4 o0 = make_float4(0.25f*tot[0]+bias[c+0], 0.25f*tot[1]+bias[c+1],
                                0.25f*tot[2]+bias[c+2], 0.25f*tot[3]+bias[c+3]);
        float4 o1 = make_float4(0.25f*tot[4]+bias[c+4], 0.25f*tot[5]+bias[c+5],
                                0.25f*tot[6]+bias[c+6], 0.25f*tot[7]+bias[c+7]);
        *(float4*)(Yout + (size_t)gw*H_ + c)     = o0;
        *(float4*)(Yout + (size_t)gw*H_ + c + 4) = o1;
      }
    } else {
      float o[8];
      float ss = 0.f;
      if (lane < 16){
        #pragma unroll
        for (int j = 0; j < 8; j++){ o[j] = 0.25f*tot[j] + bias[c+j]; ss += o[j]; }
      }
      #pragma unroll
      for (int d = 1; d < 16; d <<= 1) ss += __shfl_xor(ss, d);
      float mu = ss * (1.f/H_);
      float vv = 0.f;
      if (lane < 16){
        #pragma unroll
        for (int j = 0; j < 8; j++){ float dx = o[j]-mu; vv += dx*dx; }
      }
      #pragma unroll
      for (int d = 1; d < 16; d <<= 1) vv += __shfl_xor(vv, d);
      float inv = rsqrtf(vv*(1.f/H_) + 1e-5f);
      if (lane < 16){
        float4 g0 = *(const float4*)(lng + c), g1 = *(const float4*)(lng + c + 4);
        float4 b0 = *(const float4*)(lnb + c), b1 = *(const float4*)(lnb + c + 4);
        float gg[8] = {g0.x,g0.y,g0.z,g0.w,g1.x,g1.y,g1.z,g1.w};
        float bb[8] = {b0.x,b0.y,b0.z,b0.w,b1.x,b1.y,b1.z,b1.w};
        float oo[8];
        #pragma unroll
        for (int j = 0; j < 8; j++) oo[j] = fmaxf((o[j]-mu)*inv*gg[j] + bb[j], 0.f);
        uint4 up;
        up.x = ((unsigned int)f2b(oo[1]) << 16) | f2b(oo[0]);
        up.y = ((unsigned int)f2b(oo[3]) << 16) | f2b(oo[2]);
        up.z = ((unsigned int)f2b(oo[5]) << 16) | f2b(oo[4]);
        up.w = ((unsigned int)f2b(oo[7]) << 16) | f2b(oo[6]);
        *(uint4*)(Xbout + (size_t)gw*H_ + lane*8) = up;
        *(float4*)(&orow_s[nd][c])     = make_float4(oo[0], oo[1], oo[2], oo[3]);
        *(float4*)(&orow_s[nd][c + 4]) = make_float4(oo[4], oo[5], oo[6], oo[7]);
      }
      __builtin_amdgcn_wave_barrier();
      float pe = 0.f, pd = 0.f;
      #pragma unroll
      for (int j = 0; j < 8; j++){
        float xv = orow_s[nd][c + j];
        pe += xv * wasN[(c + j)*4 + head];
        pd += xv * wadN[(c + j)*4 + head];
      }
      #pragma unroll
      for (int d = 1; d < 16; d <<= 1){ pe += __shfl_xor(pe, d); pd += __shfl_xor(pd, d); }
      if ((lane & 15) == 0){
        esN[(size_t)gw*4 + head] = pe;
        edN[(size_t)gw*4 + head] = pd;
      }
    }
  }
}

extern "C" void kernel_launch(void* const* d_in, const int* in_sizes, int n_in,
                              void* d_out, int out_size, void* d_ws, size_t ws_size,
                              hipStream_t stream){
  const float* x0   = (const float*)d_in[0];
  const int*   srcI = (const int*)d_in[1];
  const int*   tgtI = (const int*)d_in[2];
  const float* Wl[3]  = {(const float*)d_in[3], (const float*)d_in[7],  (const float*)d_in[11]};
  const float* asl[3] = {(const float*)d_in[4], (const float*)d_in[8],  (const float*)d_in[12]};
  const float* adl[3] = {(const float*)d_in[5], (const float*)d_in[9],  (const float*)d_in[13]};
  const float* bl[3]  = {(const float*)d_in[6], (const float*)d_in[10], (const float*)d_in[14]};
  const float* lng[2] = {(const float*)d_in[15], (const float*)d_in[17]};
  const float* lnb[2] = {(const float*)d_in[16], (const float*)d_in[18]};

  char* p = (char*)d_ws;
  auto carve = [&](size_t bytes) -> void* {
    void* r = (void*)p; p += (bytes + 255) & ~(size_t)255; return r;
  };
  int*   off    = (int*)carve((size_t)B_*(N_+1)*4);
  int*   cnt    = (int*)carve((size_t)B_*N_*4);
  int*   cursor = (int*)carve((size_t)B_*N_*4);
  int*   csr    = (int*)carve((size_t)B_*E_*4);
  float* es2[2] = {(float*)carve((size_t)NROWS*4*4), (float*)carve((size_t)NROWS*4*4)};
  float* ed2[2] = {(float*)carve((size_t)NROWS*4*4), (float*)carve((size_t)NROWS*4*4)};
  float* wasA   = (float*)carve((size_t)3*HH_*4);
  float* wadA   = (float*)carve((size_t)3*HH_*4);
  unsigned short* wtA  = (unsigned short*)carve((size_t)3*HH_*H_*2);
  unsigned short* hbuf = (unsigned short*)carve((size_t)NROWS*HH_*2);
  unsigned short* xbf  = (unsigned short*)carve((size_t)NROWS*H_*2);

  hipMemsetAsync(cnt, 0, (size_t)B_*N_*4, stream);
  k_count  <<<dim3(E_/256, B_), 256, 0, stream>>>(tgtI, cnt);
  k_scan   <<<B_, 1024, 0, stream>>>(cnt, off, cursor);
  k_scatter<<<dim3(E_/256, B_), 256, 0, stream>>>(srcI, tgtI, cursor, csr);
  k_prep   <<<dim3(258, 3), 256, 0, stream>>>(Wl[0], Wl[1], Wl[2],
                                              asl[0], asl[1], asl[2],
                                              adl[0], adl[1], adl[2],
                                              wasA, wadA, wtA);
  k_cast_logits<<<NROWS/4, 256, 0, stream>>>(x0, wasA, wadA, xbf, es2[0], ed2[0]);

  for (int l = 0; l < 3; ++l){
    k_gemm_mfma<<<dim3(NROWS/64, HH_/64), 256, 0, stream>>>(xbf, wtA + (size_t)l*HH_*H_, hbuf);
    int cur = l & 1, nxt = cur ^ 1;
    if (l < 2){
      k_aggregate<false><<<NROWS/2, 256, 0, stream>>>(hbuf, es2[cur], ed2[cur], off, csr, bl[l],
          wasA + (size_t)(l+1)*HH_, wadA + (size_t)(l+1)*HH_, lng[l], lnb[l],
          nullptr, xbf, es2[nxt], ed2[nxt]);
    } else {
      k_aggregate<true><<<NROWS/2, 256, 0, stream>>>(hbuf, es2[cur], ed2[cur], off, csr, bl[l],
          nullptr, nullptr, nullptr, nullptr,
          (float*)d_out, nullptr, nullptr, nullptr);
    }
  }
}

// Round 9
// 510.963 us; speedup vs baseline: 1.0628x; 1.0628x over previous
//
#include <hip/hip_runtime.h>
#include <hip/hip_bf16.h>
#include <cstdint>
#include <cstddef>

#define B_ 4
#define N_ 10000
#define E_ 160000
#define H_ 128
#define HEADS_ 4
#define HH_ 512
#define NROWS (B_*N_)

typedef __attribute__((ext_vector_type(8))) short bf16x8;
typedef __attribute__((ext_vector_type(4))) float f32x4;
typedef __attribute__((ext_vector_type(2))) float f32x2;

__device__ __forceinline__ float lrelu(float x){ return fmaxf(x, 0.2f*x); }
__device__ __forceinline__ unsigned short f2b(float f){
  unsigned int u = __builtin_bit_cast(unsigned int, f);
  unsigned int r = (u + 0x7fffu + ((u >> 16) & 1u)) >> 16;
  return (unsigned short)r;
}
__device__ __forceinline__ float blo(unsigned int u){ return __builtin_bit_cast(float, u << 16); }
__device__ __forceinline__ float bhi(unsigned int u){ return __builtin_bit_cast(float, u & 0xffff0000u); }

__device__ __forceinline__ void acc_row(f32x2* ac, float al, uint4 h){
  f32x2 v = {al, al};
  ac[0] += v * (f32x2){blo(h.x), bhi(h.x)};
  ac[1] += v * (f32x2){blo(h.y), bhi(h.y)};
  ac[2] += v * (f32x2){blo(h.z), bhi(h.z)};
  ac[3] += v * (f32x2){blo(h.w), bhi(h.w)};
}

// ---------------- CSR build ----------------
__global__ void k_count(const int* __restrict__ tgt, int* __restrict__ cnt){
  int e = blockIdx.x*blockDim.x + threadIdx.x;
  int b = blockIdx.y;
  int t = tgt[(size_t)b*E_ + e];
  atomicAdd(&cnt[b*N_ + t], 1);
}

__global__ void k_scan(const int* __restrict__ cnt, int* __restrict__ off, int* __restrict__ cursor){
  int b = blockIdx.x;
  __shared__ int wsum[16];
  __shared__ int carry_s;
  int lane = threadIdx.x & 63, wid = threadIdx.x >> 6;
  if (threadIdx.x == 0){ carry_s = 0; off[b*(N_+1)] = 0; }
  __syncthreads();
  for (int base = 0; base < N_; base += 1024){
    int i = base + threadIdx.x;
    int v = (i < N_) ? cnt[b*N_ + i] : 0;
    int x = v;
    #pragma unroll
    for (int d = 1; d < 64; d <<= 1){
      int y = __shfl_up(x, d);
      if (lane >= d) x += y;
    }
    if (lane == 63) wsum[wid] = x;
    __syncthreads();
    if (wid == 0 && lane < 16){
      int w = wsum[lane];
      #pragma unroll
      for (int d = 1; d < 16; d <<= 1){
        int y = __shfl_up(w, d, 16);
        if (lane >= d) w += y;
      }
      wsum[lane] = w;
    }
    __syncthreads();
    int excl = (wid ? wsum[wid-1] : 0) + carry_s;
    if (i < N_){
      int inc = x + excl;
      off[b*(N_+1) + i + 1] = inc;
      cursor[b*N_ + i] = inc - v;
    }
    __syncthreads();
    if (threadIdx.x == 0) carry_s += wsum[15];
    __syncthreads();
  }
}

__global__ void k_scatter(const int* __restrict__ src, const int* __restrict__ tgt,
                          int* __restrict__ cursor, int* __restrict__ csr){
  int e = blockIdx.x*blockDim.x + threadIdx.x;
  int b = blockIdx.y;
  int t = tgt[(size_t)b*E_ + e];
  int pos = atomicAdd(&cursor[b*N_ + t], 1);
  csr[(size_t)b*E_ + pos] = src[(size_t)b*E_ + e];
}

// ---------------- prep: Wa tables + W transpose/cast, all 3 layers ----------------
__global__ void k_prep(const float* __restrict__ W0, const float* __restrict__ W1, const float* __restrict__ W2,
                       const float* __restrict__ as0, const float* __restrict__ as1, const float* __restrict__ as2,
                       const float* __restrict__ ad0, const float* __restrict__ ad1, const float* __restrict__ ad2,
                       float* __restrict__ wasA, float* __restrict__ wadA, unsigned short* __restrict__ wtA){
  int l = blockIdx.y;
  const float* W   = (l==0)?W0:(l==1)?W1:W2;
  const float* asp = (l==0)?as0:(l==1)?as1:as2;
  const float* adp = (l==0)?ad0:(l==1)?ad1:ad2;
  if (blockIdx.x < 256){
    int i = blockIdx.x*256 + threadIdx.x;     // i = c*H_ + k
    int c = i >> 7, k = i & 127;
    wtA[(size_t)l*HH_*H_ + i] = f2b(W[(size_t)k*HH_ + c]);
  } else {
    int j = (blockIdx.x - 256)*256 + threadIdx.x;   // j = k*4 + h
    if (j < H_*HEADS_){
      int k = j >> 2, h = j & 3;
      const float* wrow = W + (size_t)k*HH_ + h*H_;
      const float* asr = asp + h*H_;
      const float* adr = adp + h*H_;
      float ss = 0.f, sd = 0.f;
      for (int c = 0; c < H_; ++c){ float w = wrow[c]; ss += w*asr[c]; sd += w*adr[c]; }
      wasA[l*HH_ + j] = ss; wadA[l*HH_ + j] = sd;
    }
  }
}

// ---------------- layer-1: cast x->bf16 + logits (one wave per row) ----------------
__global__ __launch_bounds__(256) void k_cast_logits(const float* __restrict__ X,
    const float* __restrict__ was, const float* __restrict__ wad,
    unsigned short* __restrict__ Xb, float* __restrict__ es, float* __restrict__ ed){
  int gw = (blockIdx.x*blockDim.x + threadIdx.x) >> 6;
  int lane = threadIdx.x & 63;
  float2 v = *(const float2*)(X + (size_t)gw*H_ + lane*2);
  unsigned int o = ((unsigned int)f2b(v.y) << 16) | (unsigned int)f2b(v.x);
  *(unsigned int*)(Xb + (size_t)gw*H_ + lane*2) = o;
  int c = lane*2;
  const f32x4* w4 = (const f32x4*)was;
  const f32x4* d4 = (const f32x4*)wad;
  f32x4 se = v.x*w4[c] + v.y*w4[c+1];
  f32x4 de = v.x*d4[c] + v.y*d4[c+1];
  #pragma unroll
  for (int d = 1; d < 64; d <<= 1){
    se.x += __shfl_xor(se.x,d); se.y += __shfl_xor(se.y,d);
    se.z += __shfl_xor(se.z,d); se.w += __shfl_xor(se.w,d);
    de.x += __shfl_xor(de.x,d); de.y += __shfl_xor(de.y,d);
    de.z += __shfl_xor(de.z,d); de.w += __shfl_xor(de.w,d);
  }
  if (lane == 0){
    *(float4*)(es + (size_t)gw*4) = make_float4(se.x, se.y, se.z, se.w);
    *(float4*)(ed + (size_t)gw*4) = make_float4(de.x, de.y, de.z, de.w);
  }
}

// ---------------- h = x @ W  (bf16 MFMA 16x16x32; 64x64 tile) ----------------
__global__ __launch_bounds__(256) void k_gemm_mfma(const unsigned short* __restrict__ Xb,
    const unsigned short* __restrict__ Wt, unsigned short* __restrict__ Hb){
  __shared__ unsigned short xs[64*128];
  __shared__ unsigned short ws[64*128];
  int row0 = blockIdx.x * 64, col0 = blockIdx.y * 64;
  int tid = threadIdx.x;
  int ch = tid & 15, r0 = tid >> 4;
  #pragma unroll
  for (int p = 0; p < 4; ++p){
    int r = r0 + p*16;
    int sc = ch ^ (r & 7);
    *(uint4*)(&xs[r*128 + sc*8]) = *(const uint4*)(Xb + (size_t)(row0 + r)*H_ + ch*8);
    *(uint4*)(&ws[r*128 + sc*8]) = *(const uint4*)(Wt + (size_t)(col0 + r)*H_ + ch*8);
  }
  __syncthreads();
  int w = tid >> 6, l = tid & 63;
  int lr = l & 15, q = l >> 4;
  f32x4 z = {0.f, 0.f, 0.f, 0.f};
  f32x4 acc[4] = {z, z, z, z};
  int arow = w*16 + lr;
  #pragma unroll
  for (int kf = 0; kf < 4; ++kf){
    int bch = kf*4 + q;
    bf16x8 a = *(const bf16x8*)(&xs[arow*128 + (bch ^ (arow & 7))*8]);
    #pragma unroll
    for (int cf = 0; cf < 4; ++cf){
      int brow = cf*16 + lr;
      bf16x8 bfr = *(const bf16x8*)(&ws[brow*128 + (bch ^ (brow & 7))*8]);
      acc[cf] = __builtin_amdgcn_mfma_f32_16x16x32_bf16(a, bfr, acc[cf], 0, 0, 0);
    }
  }
  #pragma unroll
  for (int cf = 0; cf < 4; ++cf){
    #pragma unroll
    for (int rg = 0; rg < 4; ++rg){
      int row = row0 + w*16 + q*4 + rg;
      int col = col0 + cf*16 + lr;
      Hb[(size_t)row*HH_ + col] = f2b(acc[cf][rg]);
    }
  }
}

// ---- aggregate: one wave per node; cheap phase A (regs only) + R2-style phase B ----
template<bool FINAL>
__global__ __launch_bounds__(256) void k_aggregate(
    const unsigned short* __restrict__ Hb,
    const float* __restrict__ es, const float* __restrict__ ed,
    const int* __restrict__ off, const int* __restrict__ csr,
    const float* __restrict__ bias,
    const float* __restrict__ wasN, const float* __restrict__ wadN,
    const float* __restrict__ lng, const float* __restrict__ lnb,
    float* __restrict__ Yout, unsigned short* __restrict__ Xbout,
    float* __restrict__ esN, float* __restrict__ edN)
{
  __shared__ float orow_s[4][128];
  int wv = threadIdx.x >> 6, lane = threadIdx.x & 63;
  int gw = blockIdx.x*4 + wv;
  int b = gw / N_, t = gw - b*N_;
  const float4 edv = *(const float4*)(ed + (size_t)gw*4);
  int start = off[b*(N_+1) + t];
  int deg = off[b*(N_+1) + t + 1] - start;
  int total = deg + 1;                 // + implicit self-loop
  const int* lst = csr + (size_t)b*E_ + start;
  const float* esb = es + (size_t)b*N_*4;
  int head = lane >> 4;
  int cb = head*H_ + (lane & 15)*8;
  const unsigned short* hbase = Hb + (size_t)b*N_*HH_;
  float edh = head==0 ? edv.x : head==1 ? edv.y : head==2 ? edv.z : edv.w;
  float Lh;     // = M_h + log(S_h); alpha = exp(e - Lh)

  if (total <= 64){
    // ---- phase A: exact softmax stats, one lane per edge (cheap: 8 exps/wave) ----
    bool valid = lane < total;
    int srcn = (lane < deg) ? lst[lane] : t;
    float4 ev = *(const float4*)(esb + (size_t)srcn*4);
    float e0 = valid ? lrelu(ev.x + edv.x) : -1e30f;
    float e1 = valid ? lrelu(ev.y + edv.y) : -1e30f;
    float e2 = valid ? lrelu(ev.z + edv.z) : -1e30f;
    float e3 = valid ? lrelu(ev.w + edv.w) : -1e30f;
    float M0 = e0, M1 = e1, M2 = e2, M3 = e3;
    #pragma unroll
    for (int d = 1; d < 64; d <<= 1){
      M0 = fmaxf(M0, __shfl_xor(M0, d)); M1 = fmaxf(M1, __shfl_xor(M1, d));
      M2 = fmaxf(M2, __shfl_xor(M2, d)); M3 = fmaxf(M3, __shfl_xor(M3, d));
    }
    float p0 = valid ? __expf(e0 - M0) : 0.f;
    float p1 = valid ? __expf(e1 - M1) : 0.f;
    float p2 = valid ? __expf(e2 - M2) : 0.f;
    float p3 = valid ? __expf(e3 - M3) : 0.f;
    float S0 = p0, S1 = p1, S2 = p2, S3 = p3;
    #pragma unroll
    for (int d = 1; d < 64; d <<= 1){
      S0 += __shfl_xor(S0, d); S1 += __shfl_xor(S1, d);
      S2 += __shfl_xor(S2, d); S3 += __shfl_xor(S3, d);
    }
    float Mh = head==0 ? M0 : head==1 ? M1 : head==2 ? M2 : M3;
    float Sh = head==0 ? S0 : head==1 ? S1 : head==2 ? S2 : S3;
    Lh = Mh + __logf(Sh);
  } else {
    // ---- slow path stats: online softmax across 64-lane strides ----
    float m0=-1e30f, m1=-1e30f, m2=-1e30f, m3=-1e30f;
    float s0=0.f, s1=0.f, s2=0.f, s3=0.f;
    for (int i2 = lane; i2 <= deg; i2 += 64){
      int srcn = (i2 < deg) ? lst[i2] : t;
      float4 ev = *(const float4*)(esb + (size_t)srcn*4);
      float e0 = lrelu(ev.x + edv.x);
      float e1 = lrelu(ev.y + edv.y);
      float e2 = lrelu(ev.z + edv.z);
      float e3 = lrelu(ev.w + edv.w);
      float nm;
      nm = fmaxf(m0, e0); s0 = s0*__expf(m0-nm) + __expf(e0-nm); m0 = nm;
      nm = fmaxf(m1, e1); s1 = s1*__expf(m1-nm) + __expf(e1-nm); m1 = nm;
      nm = fmaxf(m2, e2); s2 = s2*__expf(m2-nm) + __expf(e2-nm); m2 = nm;
      nm = fmaxf(m3, e3); s3 = s3*__expf(m3-nm) + __expf(e3-nm); m3 = nm;
    }
    #pragma unroll
    for (int d = 1; d < 64; d <<= 1){
      float om, os, nm;
      om = __shfl_xor(m0, d); os = __shfl_xor(s0, d); nm = fmaxf(m0, om);
      s0 = s0*__expf(m0-nm) + os*__expf(om-nm); m0 = nm;
      om = __shfl_xor(m1, d); os = __shfl_xor(s1, d); nm = fmaxf(m1, om);
      s1 = s1*__expf(m1-nm) + os*__expf(om-nm); m1 = nm;
      om = __shfl_xor(m2, d); os = __shfl_xor(s2, d); nm = fmaxf(m2, om);
      s2 = s2*__expf(m2-nm) + os*__expf(om-nm); m2 = nm;
      om = __shfl_xor(m3, d); os = __shfl_xor(s3, d); nm = fmaxf(m3, om);
      s3 = s3*__expf(m3-nm) + os*__expf(om-nm); m3 = nm;
    }
    float Mh = head==0 ? m0 : head==1 ? m1 : head==2 ? m2 : m3;
    float Sh = head==0 ? s0 : head==1 ? s1 : head==2 ? s2 : s3;
    Lh = Mh + __logf(Sh);
  }

  // ---- phase B: R2-proven loop — inline exp (VALU hides gather latency), 2-unroll ----
  f32x2 zz = {0.f, 0.f};
  f32x2 ac[4] = {zz, zz, zz, zz};
  int i = 0;
  for (; i + 1 < total; i += 2){
    int sA = lst[i];                         // i < deg guaranteed
    int sB = (i + 1 < deg) ? lst[i+1] : t;
    float eA = esb[(size_t)sA*4 + head];
    float eB = esb[(size_t)sB*4 + head];
    uint4 hA = *(const uint4*)(hbase + (size_t)sA*HH_ + cb);
    uint4 hB = *(const uint4*)(hbase + (size_t)sB*HH_ + cb);
    float aA = __expf(lrelu(eA + edh) - Lh);
    float aB = __expf(lrelu(eB + edh) - Lh);
    acc_row(ac, aA, hA);
    acc_row(ac, aB, hB);
  }
  if (i < total){
    int sA = (i < deg) ? lst[i] : t;
    float eA = esb[(size_t)sA*4 + head];
    uint4 hA = *(const uint4*)(hbase + (size_t)sA*HH_ + cb);
    float aA = __expf(lrelu(eA + edh) - Lh);
    acc_row(ac, aA, hA);
  }

  // ---- head mean ----
  float a[8] = {ac[0].x, ac[0].y, ac[1].x, ac[1].y, ac[2].x, ac[2].y, ac[3].x, ac[3].y};
  #pragma unroll
  for (int d = 16; d < 64; d <<= 1)
    #pragma unroll
    for (int j = 0; j < 8; j++) a[j] += __shfl_xor(a[j], d);

  int c = (lane & 15)*8;
  if (FINAL){
    if (lane < 16){
      float4 o0 = make_float4(0.25f*a[0]+bias[c+0], 0.25f*a[1]+bias[c+1],
                              0.25f*a[2]+bias[c+2], 0.25f*a[3]+bias[c+3]);
      float4 o1 = make_float4(0.25f*a[4]+bias[c+4], 0.25f*a[5]+bias[c+5],
                              0.25f*a[6]+bias[c+6], 0.25f*a[7]+bias[c+7]);
      *(float4*)(Yout + (size_t)gw*H_ + c)     = o0;
      *(float4*)(Yout + (size_t)gw*H_ + c + 4) = o1;
    }
  } else {
    float o[8];
    #pragma unroll
    for (int j = 0; j < 8; j++) o[j] = 0.25f*a[j] + bias[c+j];
    float ss = 0.f;
    #pragma unroll
    for (int j = 0; j < 8; j++) ss += o[j];
    #pragma unroll
    for (int d = 1; d < 16; d <<= 1) ss += __shfl_xor(ss, d);
    float mu = ss * (1.f/H_);
    float vv = 0.f;
    #pragma unroll
    for (int j = 0; j < 8; j++){ float dx = o[j]-mu; vv += dx*dx; }
    #pragma unroll
    for (int d = 1; d < 16; d <<= 1) vv += __shfl_xor(vv, d);
    float inv = rsqrtf(vv*(1.f/H_) + 1e-5f);
    float4 g0 = *(const float4*)(lng + c), g1 = *(const float4*)(lng + c + 4);
    float4 b0 = *(const float4*)(lnb + c), b1 = *(const float4*)(lnb + c + 4);
    float gg[8] = {g0.x,g0.y,g0.z,g0.w,g1.x,g1.y,g1.z,g1.w};
    float bb[8] = {b0.x,b0.y,b0.z,b0.w,b1.x,b1.y,b1.z,b1.w};
    float oo[8];
    #pragma unroll
    for (int j = 0; j < 8; j++) oo[j] = fmaxf((o[j]-mu)*inv*gg[j] + bb[j], 0.f);
    if (lane < 16){
      uint4 up;
      up.x = ((unsigned int)f2b(oo[1]) << 16) | f2b(oo[0]);
      up.y = ((unsigned int)f2b(oo[3]) << 16) | f2b(oo[2]);
      up.z = ((unsigned int)f2b(oo[5]) << 16) | f2b(oo[4]);
      up.w = ((unsigned int)f2b(oo[7]) << 16) | f2b(oo[6]);
      *(uint4*)(Xbout + (size_t)gw*H_ + lane*8) = up;
      *(float4*)(&orow_s[wv][c])     = make_float4(oo[0], oo[1], oo[2], oo[3]);
      *(float4*)(&orow_s[wv][c + 4]) = make_float4(oo[4], oo[5], oo[6], oo[7]);
    }
    __builtin_amdgcn_wave_barrier();
    float pe = 0.f, pd = 0.f;
    #pragma unroll
    for (int j = 0; j < 8; j++){
      float xv = orow_s[wv][c + j];
      pe += xv * wasN[(c + j)*4 + head];
      pd += xv * wadN[(c + j)*4 + head];
    }
    #pragma unroll
    for (int d = 1; d < 16; d <<= 1){ pe += __shfl_xor(pe, d); pd += __shfl_xor(pd, d); }
    if ((lane & 15) == 0){
      esN[(size_t)gw*4 + head] = pe;
      edN[(size_t)gw*4 + head] = pd;
    }
  }
}

extern "C" void kernel_launch(void* const* d_in, const int* in_sizes, int n_in,
                              void* d_out, int out_size, void* d_ws, size_t ws_size,
                              hipStream_t stream){
  const float* x0   = (const float*)d_in[0];
  const int*   srcI = (const int*)d_in[1];
  const int*   tgtI = (const int*)d_in[2];
  const float* Wl[3]  = {(const float*)d_in[3], (const float*)d_in[7],  (const float*)d_in[11]};
  const float* asl[3] = {(const float*)d_in[4], (const float*)d_in[8],  (const float*)d_in[12]};
  const float* adl[3] = {(const float*)d_in[5], (const float*)d_in[9],  (const float*)d_in[13]};
  const float* bl[3]  = {(const float*)d_in[6], (const float*)d_in[10], (const float*)d_in[14]};
  const float* lng[2] = {(const float*)d_in[15], (const float*)d_in[17]};
  const float* lnb[2] = {(const float*)d_in[16], (const float*)d_in[18]};

  char* p = (char*)d_ws;
  auto carve = [&](size_t bytes) -> void* {
    void* r = (void*)p; p += (bytes + 255) & ~(size_t)255; return r;
  };
  int*   off    = (int*)carve((size_t)B_*(N_+1)*4);
  int*   cnt    = (int*)carve((size_t)B_*N_*4);
  int*   cursor = (int*)carve((size_t)B_*N_*4);
  int*   csr    = (int*)carve((size_t)B_*E_*4);
  float* es2[2] = {(float*)carve((size_t)NROWS*4*4), (float*)carve((size_t)NROWS*4*4)};
  float* ed2[2] = {(float*)carve((size_t)NROWS*4*4), (float*)carve((size_t)NROWS*4*4)};
  float* wasA   = (float*)carve((size_t)3*HH_*4);
  float* wadA   = (float*)carve((size_t)3*HH_*4);
  unsigned short* wtA  = (unsigned short*)carve((size_t)3*HH_*H_*2);
  unsigned short* hbuf = (unsigned short*)carve((size_t)NROWS*HH_*2);
  unsigned short* xbf  = (unsigned short*)carve((size_t)NROWS*H_*2);

  hipMemsetAsync(cnt, 0, (size_t)B_*N_*4, stream);
  k_count  <<<dim3(E_/256, B_), 256, 0, stream>>>(tgtI, cnt);
  k_scan   <<<B_, 1024, 0, stream>>>(cnt, off, cursor);
  k_scatter<<<dim3(E_/256, B_), 256, 0, stream>>>(srcI, tgtI, cursor, csr);
  k_prep   <<<dim3(258, 3), 256, 0, stream>>>(Wl[0], Wl[1], Wl[2],
                                              asl[0], asl[1], asl[2],
                                              adl[0], adl[1], adl[2],
                                              wasA, wadA, wtA);
  k_cast_logits<<<NROWS/4, 256, 0, stream>>>(x0, wasA, wadA, xbf, es2[0], ed2[0]);

  for (int l = 0; l < 3; ++l){
    k_gemm_mfma<<<dim3(NROWS/64, HH_/64), 256, 0, stream>>>(xbf, wtA + (size_t)l*HH_*H_, hbuf);
    int cur = l & 1, nxt = cur ^ 1;
    if (l < 2){
      k_aggregate<false><<<NROWS/4, 256, 0, stream>>>(hbuf, es2[cur], ed2[cur], off, csr, bl[l],
          wasA + (size_t)(l+1)*HH_, wadA + (size_t)(l+1)*HH_, lng[l], lnb[l],
          nullptr, xbf, es2[nxt], ed2[nxt]);
    } else {
      k_aggregate<true><<<NROWS/4, 256, 0, stream>>>(hbuf, es2[cur], ed2[cur], off, csr, bl[l],
          nullptr, nullptr, nullptr, nullptr,
          (float*)d_out, nullptr, nullptr, nullptr);
    }
  }
}

// Round 10
// 484.345 us; speedup vs baseline: 1.1212x; 1.0550x over previous
//
#include <hip/hip_runtime.h>
#include <hip/hip_bf16.h>
#include <cstdint>
#include <cstddef>

#define B_ 4
#define N_ 10000
#define E_ 160000
#define H_ 128
#define HEADS_ 4
#define HH_ 512
#define NROWS (B_*N_)

typedef __attribute__((ext_vector_type(8))) short bf16x8;
typedef __attribute__((ext_vector_type(4))) float f32x4;
typedef __attribute__((ext_vector_type(2))) float f32x2;

__device__ __forceinline__ float lrelu(float x){ return x > 0.f ? x : 0.2f*x; }
__device__ __forceinline__ unsigned short f2b(float f){
  unsigned int u = __builtin_bit_cast(unsigned int, f);
  unsigned int r = (u + 0x7fffu + ((u >> 16) & 1u)) >> 16;
  return (unsigned short)r;
}
__device__ __forceinline__ float blo(unsigned int u){ return __builtin_bit_cast(float, u << 16); }
__device__ __forceinline__ float bhi(unsigned int u){ return __builtin_bit_cast(float, u & 0xffff0000u); }

// ---------------- CSR build ----------------
__global__ void k_count(const int* __restrict__ tgt, int* __restrict__ cnt){
  int e = blockIdx.x*blockDim.x + threadIdx.x;
  int b = blockIdx.y;
  int t = tgt[(size_t)b*E_ + e];
  atomicAdd(&cnt[b*N_ + t], 1);
}

__global__ void k_scan(const int* __restrict__ cnt, int* __restrict__ off, int* __restrict__ cursor){
  int b = blockIdx.x;
  __shared__ int wsum[16];
  __shared__ int carry_s;
  int lane = threadIdx.x & 63, wid = threadIdx.x >> 6;
  if (threadIdx.x == 0){ carry_s = 0; off[b*(N_+1)] = 0; }
  __syncthreads();
  for (int base = 0; base < N_; base += 1024){
    int i = base + threadIdx.x;
    int v = (i < N_) ? cnt[b*N_ + i] : 0;
    int x = v;
    #pragma unroll
    for (int d = 1; d < 64; d <<= 1){
      int y = __shfl_up(x, d);
      if (lane >= d) x += y;
    }
    if (lane == 63) wsum[wid] = x;
    __syncthreads();
    if (wid == 0 && lane < 16){
      int w = wsum[lane];
      #pragma unroll
      for (int d = 1; d < 16; d <<= 1){
        int y = __shfl_up(w, d, 16);
        if (lane >= d) w += y;
      }
      wsum[lane] = w;
    }
    __syncthreads();
    int excl = (wid ? wsum[wid-1] : 0) + carry_s;
    if (i < N_){
      int inc = x + excl;
      off[b*(N_+1) + i + 1] = inc;
      cursor[b*N_ + i] = inc - v;
    }
    __syncthreads();
    if (threadIdx.x == 0) carry_s += wsum[15];
    __syncthreads();
  }
}

__global__ void k_scatter(const int* __restrict__ src, const int* __restrict__ tgt,
                          int* __restrict__ cursor, int* __restrict__ csr){
  int e = blockIdx.x*blockDim.x + threadIdx.x;
  int b = blockIdx.y;
  int t = tgt[(size_t)b*E_ + e];
  int pos = atomicAdd(&cursor[b*N_ + t], 1);
  csr[(size_t)b*E_ + pos] = src[(size_t)b*E_ + e];
}

// ---------------- prep: Wa tables + W transpose/cast, all 3 layers ----------------
__global__ void k_prep(const float* __restrict__ W0, const float* __restrict__ W1, const float* __restrict__ W2,
                       const float* __restrict__ as0, const float* __restrict__ as1, const float* __restrict__ as2,
                       const float* __restrict__ ad0, const float* __restrict__ ad1, const float* __restrict__ ad2,
                       float* __restrict__ wasA, float* __restrict__ wadA, unsigned short* __restrict__ wtA){
  int l = blockIdx.y;
  const float* W   = (l==0)?W0:(l==1)?W1:W2;
  const float* asp = (l==0)?as0:(l==1)?as1:as2;
  const float* adp = (l==0)?ad0:(l==1)?ad1:ad2;
  if (blockIdx.x < 256){
    int i = blockIdx.x*256 + threadIdx.x;     // i = c*H_ + k
    int c = i >> 7, k = i & 127;
    wtA[(size_t)l*HH_*H_ + i] = f2b(W[(size_t)k*HH_ + c]);
  } else {
    int j = (blockIdx.x - 256)*256 + threadIdx.x;   // j = k*4 + h
    if (j < H_*HEADS_){
      int k = j >> 2, h = j & 3;
      const float* wrow = W + (size_t)k*HH_ + h*H_;
      const float* asr = asp + h*H_;
      const float* adr = adp + h*H_;
      float ss = 0.f, sd = 0.f;
      for (int c = 0; c < H_; ++c){ float w = wrow[c]; ss += w*asr[c]; sd += w*adr[c]; }
      wasA[l*HH_ + j] = ss; wadA[l*HH_ + j] = sd;
    }
  }
}

// ---------------- layer-1: cast x->bf16 + logits (one wave per row) ----------------
__global__ __launch_bounds__(256) void k_cast_logits(const float* __restrict__ X,
    const float* __restrict__ was, const float* __restrict__ wad,
    unsigned short* __restrict__ Xb, float* __restrict__ es, float* __restrict__ ed){
  int gw = (blockIdx.x*blockDim.x + threadIdx.x) >> 6;
  int lane = threadIdx.x & 63;
  float2 v = *(const float2*)(X + (size_t)gw*H_ + lane*2);
  unsigned int o = ((unsigned int)f2b(v.y) << 16) | (unsigned int)f2b(v.x);
  *(unsigned int*)(Xb + (size_t)gw*H_ + lane*2) = o;
  int c = lane*2;
  const f32x4* w4 = (const f32x4*)was;
  const f32x4* d4 = (const f32x4*)wad;
  f32x4 se = v.x*w4[c] + v.y*w4[c+1];
  f32x4 de = v.x*d4[c] + v.y*d4[c+1];
  #pragma unroll
  for (int d = 1; d < 64; d <<= 1){
    se.x += __shfl_xor(se.x,d); se.y += __shfl_xor(se.y,d);
    se.z += __shfl_xor(se.z,d); se.w += __shfl_xor(se.w,d);
    de.x += __shfl_xor(de.x,d); de.y += __shfl_xor(de.y,d);
    de.z += __shfl_xor(de.z,d); de.w += __shfl_xor(de.w,d);
  }
  if (lane == 0){
    *(float4*)(es + (size_t)gw*4) = make_float4(se.x, se.y, se.z, se.w);
    *(float4*)(ed + (size_t)gw*4) = make_float4(de.x, de.y, de.z, de.w);
  }
}

// ---------------- logits for layers 2,3 (bf16 input, one wave per row) ----------------
__global__ __launch_bounds__(256) void k_logits(const unsigned short* __restrict__ Xb,
    const float* __restrict__ was, const float* __restrict__ wad,
    float* __restrict__ es, float* __restrict__ ed){
  int gw = (blockIdx.x * blockDim.x + threadIdx.x) >> 6;
  int lane = threadIdx.x & 63;
  unsigned int u = *(const unsigned int*)(Xb + (size_t)gw*H_ + lane*2);
  float xlo = blo(u), xhi = bhi(u);
  int c = lane*2;
  const f32x4* w4 = (const f32x4*)was;
  const f32x4* d4 = (const f32x4*)wad;
  f32x4 se = xlo*w4[c] + xhi*w4[c+1];
  f32x4 de = xlo*d4[c] + xhi*d4[c+1];
  #pragma unroll
  for (int d = 1; d < 64; d <<= 1){
    se.x += __shfl_xor(se.x,d); se.y += __shfl_xor(se.y,d);
    se.z += __shfl_xor(se.z,d); se.w += __shfl_xor(se.w,d);
    de.x += __shfl_xor(de.x,d); de.y += __shfl_xor(de.y,d);
    de.z += __shfl_xor(de.z,d); de.w += __shfl_xor(de.w,d);
  }
  if (lane == 0){
    *(float4*)(es + (size_t)gw*4) = make_float4(se.x, se.y, se.z, se.w);
    *(float4*)(ed + (size_t)gw*4) = make_float4(de.x, de.y, de.z, de.w);
  }
}

// ---------------- h = x @ W  (bf16 MFMA 16x16x32; 64x64 tile) ----------------
__global__ __launch_bounds__(256) void k_gemm_mfma(const unsigned short* __restrict__ Xb,
    const unsigned short* __restrict__ Wt, unsigned short* __restrict__ Hb){
  __shared__ unsigned short xs[64*128];
  __shared__ unsigned short ws[64*128];
  int row0 = blockIdx.x * 64, col0 = blockIdx.y * 64;
  int tid = threadIdx.x;
  int ch = tid & 15, r0 = tid >> 4;
  #pragma unroll
  for (int p = 0; p < 4; ++p){
    int r = r0 + p*16;
    int sc = ch ^ (r & 7);
    *(uint4*)(&xs[r*128 + sc*8]) = *(const uint4*)(Xb + (size_t)(row0 + r)*H_ + ch*8);
    *(uint4*)(&ws[r*128 + sc*8]) = *(const uint4*)(Wt + (size_t)(col0 + r)*H_ + ch*8);
  }
  __syncthreads();
  int w = tid >> 6, l = tid & 63;
  int lr = l & 15, q = l >> 4;
  f32x4 z = {0.f, 0.f, 0.f, 0.f};
  f32x4 acc[4] = {z, z, z, z};
  int arow = w*16 + lr;
  #pragma unroll
  for (int kf = 0; kf < 4; ++kf){
    int bch = kf*4 + q;
    bf16x8 a = *(const bf16x8*)(&xs[arow*128 + (bch ^ (arow & 7))*8]);
    #pragma unroll
    for (int cf = 0; cf < 4; ++cf){
      int brow = cf*16 + lr;
      bf16x8 bfr = *(const bf16x8*)(&ws[brow*128 + (bch ^ (brow & 7))*8]);
      acc[cf] = __builtin_amdgcn_mfma_f32_16x16x32_bf16(a, bfr, acc[cf], 0, 0, 0);
    }
  }
  #pragma unroll
  for (int cf = 0; cf < 4; ++cf){
    #pragma unroll
    for (int rg = 0; rg < 4; ++rg){
      int row = row0 + w*16 + q*4 + rg;
      int col = col0 + cf*16 + lr;
      Hb[(size_t)row*HH_ + col] = f2b(acc[cf][rg]);
    }
  }
}

// ---------------- aggregate: R2-verbatim (online softmax A + inline-exp B) ----------------
__global__ __launch_bounds__(256) void k_aggregate(const unsigned short* __restrict__ Hb,
    const float* __restrict__ es, const float* __restrict__ ed,
    const int* __restrict__ off, const int* __restrict__ csr,
    const float* __restrict__ bias, float* __restrict__ Y){
  int gw = (blockIdx.x * blockDim.x + threadIdx.x) >> 6;
  int lane = threadIdx.x & 63;
  int b = gw / N_;
  int t = gw - b*N_;
  const float4 edv = *(const float4*)(ed + (size_t)gw*4);
  int start = off[b*(N_+1) + t];
  int deg = off[b*(N_+1) + t + 1] - start;
  const int* lst = csr + (size_t)b*E_ + start;

  // phase A: online softmax stats
  float m0=-1e30f, m1=-1e30f, m2=-1e30f, m3=-1e30f;
  float s0=0.f, s1=0.f, s2=0.f, s3=0.f;
  for (int i = lane; i <= deg; i += 64){
    int srcn = (i < deg) ? lst[i] : t;
    float4 ev = *(const float4*)(es + (size_t)(b*N_ + srcn)*4);
    float e0 = lrelu(ev.x + edv.x);
    float e1 = lrelu(ev.y + edv.y);
    float e2 = lrelu(ev.z + edv.z);
    float e3 = lrelu(ev.w + edv.w);
    float nm;
    nm = fmaxf(m0, e0); s0 = s0*__expf(m0-nm) + __expf(e0-nm); m0 = nm;
    nm = fmaxf(m1, e1); s1 = s1*__expf(m1-nm) + __expf(e1-nm); m1 = nm;
    nm = fmaxf(m2, e2); s2 = s2*__expf(m2-nm) + __expf(e2-nm); m2 = nm;
    nm = fmaxf(m3, e3); s3 = s3*__expf(m3-nm) + __expf(e3-nm); m3 = nm;
  }
  #pragma unroll
  for (int d = 1; d < 64; d <<= 1){
    float om, os, nm;
    om = __shfl_xor(m0, d); os = __shfl_xor(s0, d); nm = fmaxf(m0, om);
    s0 = s0*__expf(m0-nm) + os*__expf(om-nm); m0 = nm;
    om = __shfl_xor(m1, d); os = __shfl_xor(s1, d); nm = fmaxf(m1, om);
    s1 = s1*__expf(m1-nm) + os*__expf(om-nm); m1 = nm;
    om = __shfl_xor(m2, d); os = __shfl_xor(s2, d); nm = fmaxf(m2, om);
    s2 = s2*__expf(m2-nm) + os*__expf(om-nm); m2 = nm;
    om = __shfl_xor(m3, d); os = __shfl_xor(s3, d); nm = fmaxf(m3, om);
    s3 = s3*__expf(m3-nm) + os*__expf(om-nm); m3 = nm;
  }

  // phase B: weighted sum over bf16 h rows. lane -> (head = lane/16, 8 channels)
  int head = lane >> 4;
  float mh, sh, edh;
  if      (head == 0){ mh = m0; sh = s0; edh = edv.x; }
  else if (head == 1){ mh = m1; sh = s1; edh = edv.y; }
  else if (head == 2){ mh = m2; sh = s2; edh = edv.z; }
  else               { mh = m3; sh = s3; edh = edv.w; }
  float rh = 1.0f / sh;
  int cb = head*H_ + (lane & 15)*8;
  const unsigned short* hbase = Hb + (size_t)b*N_*HH_;
  const float* esb = es + (size_t)b*N_*4;
  float a[8] = {0.f,0.f,0.f,0.f,0.f,0.f,0.f,0.f};
  int total = deg + 1;    // + implicit self-loop
  int i = 0;
  for (; i + 1 < total; i += 2){
    int sA = lst[i];                       // i < deg guaranteed
    int sB = (i + 1 < deg) ? lst[i+1] : t;
    float eA = esb[(size_t)sA*4 + head];
    float eB = esb[(size_t)sB*4 + head];
    uint4 hA = *(const uint4*)(hbase + (size_t)sA*HH_ + cb);
    uint4 hB = *(const uint4*)(hbase + (size_t)sB*HH_ + cb);
    float aA = __expf(lrelu(eA + edh) - mh) * rh;
    float aB = __expf(lrelu(eB + edh) - mh) * rh;
    a[0] += aA*blo(hA.x); a[1] += aA*bhi(hA.x);
    a[2] += aA*blo(hA.y); a[3] += aA*bhi(hA.y);
    a[4] += aA*blo(hA.z); a[5] += aA*bhi(hA.z);
    a[6] += aA*blo(hA.w); a[7] += aA*bhi(hA.w);
    a[0] += aB*blo(hB.x); a[1] += aB*bhi(hB.x);
    a[2] += aB*blo(hB.y); a[3] += aB*bhi(hB.y);
    a[4] += aB*blo(hB.z); a[5] += aB*bhi(hB.z);
    a[6] += aB*blo(hB.w); a[7] += aB*bhi(hB.w);
  }
  if (i < total){
    int sA = (i < deg) ? lst[i] : t;
    float eA = esb[(size_t)sA*4 + head];
    uint4 hA = *(const uint4*)(hbase + (size_t)sA*HH_ + cb);
    float aA = __expf(lrelu(eA + edh) - mh) * rh;
    a[0] += aA*blo(hA.x); a[1] += aA*bhi(hA.x);
    a[2] += aA*blo(hA.y); a[3] += aA*bhi(hA.y);
    a[4] += aA*blo(hA.z); a[5] += aA*bhi(hA.z);
    a[6] += aA*blo(hA.w); a[7] += aA*bhi(hA.w);
  }
  // head mean
  #pragma unroll
  for (int d = 16; d < 64; d <<= 1)
    #pragma unroll
    for (int j = 0; j < 8; j++) a[j] += __shfl_xor(a[j], d);
  if (lane < 16){
    int c = lane*8;
    float4 o0 = make_float4(0.25f*a[0]+bias[c+0], 0.25f*a[1]+bias[c+1],
                            0.25f*a[2]+bias[c+2], 0.25f*a[3]+bias[c+3]);
    float4 o1 = make_float4(0.25f*a[4]+bias[c+4], 0.25f*a[5]+bias[c+5],
                            0.25f*a[6]+bias[c+6], 0.25f*a[7]+bias[c+7]);
    *(float4*)(Y + (size_t)gw*H_ + c)     = o0;
    *(float4*)(Y + (size_t)gw*H_ + c + 4) = o1;
  }
}

// ---------------- LayerNorm + ReLU: read f32, write bf16 (next layer's input) ----------------
__global__ __launch_bounds__(256) void k_lnrelu(const float* __restrict__ Y,
    const float* __restrict__ g, const float* __restrict__ bb, unsigned short* __restrict__ Xb){
  int gw = (blockIdx.x*blockDim.x + threadIdx.x) >> 6;
  int lane = threadIdx.x & 63;
  float2 v = *(const float2*)(Y + (size_t)gw*H_ + lane*2);
  float sum = v.x + v.y;
  #pragma unroll
  for (int d = 1; d < 64; d <<= 1) sum += __shfl_xor(sum, d);
  float mu = sum * (1.f/H_);
  float dx = v.x - mu, dy = v.y - mu;
  float vs = dx*dx + dy*dy;
  #pragma unroll
  for (int d = 1; d < 64; d <<= 1) vs += __shfl_xor(vs, d);
  float inv = rsqrtf(vs*(1.f/H_) + 1e-5f);
  float2 gv = *(const float2*)(g + lane*2);
  float2 bv = *(const float2*)(bb + lane*2);
  float ox = fmaxf(dx*inv*gv.x + bv.x, 0.f);
  float oy = fmaxf(dy*inv*gv.y + bv.y, 0.f);
  unsigned int o = ((unsigned int)f2b(oy) << 16) | (unsigned int)f2b(ox);
  *(unsigned int*)(Xb + (size_t)gw*H_ + lane*2) = o;
}

extern "C" void kernel_launch(void* const* d_in, const int* in_sizes, int n_in,
                              void* d_out, int out_size, void* d_ws, size_t ws_size,
                              hipStream_t stream){
  const float* x0   = (const float*)d_in[0];
  const int*   srcI = (const int*)d_in[1];
  const int*   tgtI = (const int*)d_in[2];
  const float* Wl[3]  = {(const float*)d_in[3], (const float*)d_in[7],  (const float*)d_in[11]};
  const float* asl[3] = {(const float*)d_in[4], (const float*)d_in[8],  (const float*)d_in[12]};
  const float* adl[3] = {(const float*)d_in[5], (const float*)d_in[9],  (const float*)d_in[13]};
  const float* bl[3]  = {(const float*)d_in[6], (const float*)d_in[10], (const float*)d_in[14]};
  const float* lng[2] = {(const float*)d_in[15], (const float*)d_in[17]};
  const float* lnb[2] = {(const float*)d_in[16], (const float*)d_in[18]};

  char* p = (char*)d_ws;
  auto carve = [&](size_t bytes) -> void* {
    void* r = (void*)p; p += (bytes + 255) & ~(size_t)255; return r;
  };
  int*   off    = (int*)carve((size_t)B_*(N_+1)*4);
  int*   cnt    = (int*)carve((size_t)B_*N_*4);
  int*   cursor = (int*)carve((size_t)B_*N_*4);
  int*   csr    = (int*)carve((size_t)B_*E_*4);
  float* es     = (float*)carve((size_t)NROWS*4*4);
  float* ed     = (float*)carve((size_t)NROWS*4*4);
  float* wasA   = (float*)carve((size_t)3*HH_*4);
  float* wadA   = (float*)carve((size_t)3*HH_*4);
  unsigned short* wtA  = (unsigned short*)carve((size_t)3*HH_*H_*2);
  unsigned short* hbuf = (unsigned short*)carve((size_t)NROWS*HH_*2);
  unsigned short* xbf  = (unsigned short*)carve((size_t)NROWS*H_*2);
  float* tbuf   = (float*)carve((size_t)NROWS*H_*4);

  hipMemsetAsync(cnt, 0, (size_t)B_*N_*4, stream);
  k_count  <<<dim3(E_/256, B_), 256, 0, stream>>>(tgtI, cnt);
  k_scan   <<<B_, 1024, 0, stream>>>(cnt, off, cursor);
  k_scatter<<<dim3(E_/256, B_), 256, 0, stream>>>(srcI, tgtI, cursor, csr);
  k_prep   <<<dim3(258, 3), 256, 0, stream>>>(Wl[0], Wl[1], Wl[2],
                                              asl[0], asl[1], asl[2],
                                              adl[0], adl[1], adl[2],
                                              wasA, wadA, wtA);
  k_cast_logits<<<NROWS/4, 256, 0, stream>>>(x0, wasA, wadA, xbf, es, ed);

  for (int l = 0; l < 3; ++l){
    k_gemm_mfma<<<dim3(NROWS/64, HH_/64), 256, 0, stream>>>(xbf, wtA + (size_t)l*HH_*H_, hbuf);
    float* yout = (l == 2) ? (float*)d_out : tbuf;
    k_aggregate<<<NROWS/4, 256, 0, stream>>>(hbuf, es, ed, off, csr, bl[l], yout);
    if (l < 2){
      k_lnrelu<<<NROWS/4, 256, 0, stream>>>(tbuf, lng[l], lnb[l], xbf);
      k_logits<<<NROWS/4, 256, 0, stream>>>(xbf, wasA + (size_t)(l+1)*HH_, wadA + (size_t)(l+1)*HH_, es, ed);
    }
  }
}

// Round 11
// 456.280 us; speedup vs baseline: 1.1901x; 1.0615x over previous
//
#include <hip/hip_runtime.h>
#include <hip/hip_bf16.h>
#include <cstdint>
#include <cstddef>

#define B_ 4
#define N_ 10000
#define E_ 160000
#define H_ 128
#define HEADS_ 4
#define HH_ 512
#define NROWS (B_*N_)

typedef __attribute__((ext_vector_type(8))) short bf16x8;
typedef __attribute__((ext_vector_type(4))) float f32x4;
typedef __attribute__((ext_vector_type(2))) float f32x2;

__device__ __forceinline__ float lrelu(float x){ return x > 0.f ? x : 0.2f*x; }
__device__ __forceinline__ unsigned short f2b(float f){
  unsigned int u = __builtin_bit_cast(unsigned int, f);
  unsigned int r = (u + 0x7fffu + ((u >> 16) & 1u)) >> 16;
  return (unsigned short)r;
}
__device__ __forceinline__ float blo(unsigned int u){ return __builtin_bit_cast(float, u << 16); }
__device__ __forceinline__ float bhi(unsigned int u){ return __builtin_bit_cast(float, u & 0xffff0000u); }

// ---------------- CSR build ----------------
__global__ void k_count(const int* __restrict__ tgt, int* __restrict__ cnt){
  int e = blockIdx.x*blockDim.x + threadIdx.x;
  int b = blockIdx.y;
  int t = tgt[(size_t)b*E_ + e];
  atomicAdd(&cnt[b*N_ + t], 1);
}

__global__ void k_scan(const int* __restrict__ cnt, int* __restrict__ off, int* __restrict__ cursor){
  int b = blockIdx.x;
  __shared__ int wsum[16];
  __shared__ int carry_s;
  int lane = threadIdx.x & 63, wid = threadIdx.x >> 6;
  if (threadIdx.x == 0){ carry_s = 0; off[b*(N_+1)] = 0; }
  __syncthreads();
  for (int base = 0; base < N_; base += 1024){
    int i = base + threadIdx.x;
    int v = (i < N_) ? cnt[b*N_ + i] : 0;
    int x = v;
    #pragma unroll
    for (int d = 1; d < 64; d <<= 1){
      int y = __shfl_up(x, d);
      if (lane >= d) x += y;
    }
    if (lane == 63) wsum[wid] = x;
    __syncthreads();
    if (wid == 0 && lane < 16){
      int w = wsum[lane];
      #pragma unroll
      for (int d = 1; d < 16; d <<= 1){
        int y = __shfl_up(w, d, 16);
        if (lane >= d) w += y;
      }
      wsum[lane] = w;
    }
    __syncthreads();
    int excl = (wid ? wsum[wid-1] : 0) + carry_s;
    if (i < N_){
      int inc = x + excl;
      off[b*(N_+1) + i + 1] = inc;
      cursor[b*N_ + i] = inc - v;
    }
    __syncthreads();
    if (threadIdx.x == 0) carry_s += wsum[15];
    __syncthreads();
  }
}

__global__ void k_scatter(const int* __restrict__ src, const int* __restrict__ tgt,
                          int* __restrict__ cursor, int* __restrict__ csr){
  int e = blockIdx.x*blockDim.x + threadIdx.x;
  int b = blockIdx.y;
  int t = tgt[(size_t)b*E_ + e];
  int pos = atomicAdd(&cursor[b*N_ + t], 1);
  csr[(size_t)b*E_ + pos] = src[(size_t)b*E_ + e];
}

// ---------------- prep: Wa tables + W transpose/cast, all 3 layers ----------------
__global__ void k_prep(const float* __restrict__ W0, const float* __restrict__ W1, const float* __restrict__ W2,
                       const float* __restrict__ as0, const float* __restrict__ as1, const float* __restrict__ as2,
                       const float* __restrict__ ad0, const float* __restrict__ ad1, const float* __restrict__ ad2,
                       float* __restrict__ wasA, float* __restrict__ wadA, unsigned short* __restrict__ wtA){
  int l = blockIdx.y;
  const float* W   = (l==0)?W0:(l==1)?W1:W2;
  const float* asp = (l==0)?as0:(l==1)?as1:as2;
  const float* adp = (l==0)?ad0:(l==1)?ad1:ad2;
  if (blockIdx.x < 256){
    int i = blockIdx.x*256 + threadIdx.x;     // i = c*H_ + k
    int c = i >> 7, k = i & 127;
    wtA[(size_t)l*HH_*H_ + i] = f2b(W[(size_t)k*HH_ + c]);
  } else {
    int j = (blockIdx.x - 256)*256 + threadIdx.x;   // j = k*4 + h
    if (j < H_*HEADS_){
      int k = j >> 2, h = j & 3;
      const float* wrow = W + (size_t)k*HH_ + h*H_;
      const float* asr = asp + h*H_;
      const float* adr = adp + h*H_;
      float ss = 0.f, sd = 0.f;
      for (int c = 0; c < H_; ++c){ float w = wrow[c]; ss += w*asr[c]; sd += w*adr[c]; }
      wasA[l*HH_ + j] = ss; wadA[l*HH_ + j] = sd;
    }
  }
}

// ---------------- layer-1: cast x->bf16 + logits (one wave per row) ----------------
__global__ __launch_bounds__(256) void k_cast_logits(const float* __restrict__ X,
    const float* __restrict__ was, const float* __restrict__ wad,
    unsigned short* __restrict__ Xb, float* __restrict__ es, float* __restrict__ ed){
  int gw = (blockIdx.x*blockDim.x + threadIdx.x) >> 6;
  int lane = threadIdx.x & 63;
  float2 v = *(const float2*)(X + (size_t)gw*H_ + lane*2);
  unsigned int o = ((unsigned int)f2b(v.y) << 16) | (unsigned int)f2b(v.x);
  *(unsigned int*)(Xb + (size_t)gw*H_ + lane*2) = o;
  int c = lane*2;
  const f32x4* w4 = (const f32x4*)was;
  const f32x4* d4 = (const f32x4*)wad;
  f32x4 se = v.x*w4[c] + v.y*w4[c+1];
  f32x4 de = v.x*d4[c] + v.y*d4[c+1];
  #pragma unroll
  for (int d = 1; d < 64; d <<= 1){
    se.x += __shfl_xor(se.x,d); se.y += __shfl_xor(se.y,d);
    se.z += __shfl_xor(se.z,d); se.w += __shfl_xor(se.w,d);
    de.x += __shfl_xor(de.x,d); de.y += __shfl_xor(de.y,d);
    de.z += __shfl_xor(de.z,d); de.w += __shfl_xor(de.w,d);
  }
  if (lane == 0){
    *(float4*)(es + (size_t)gw*4) = make_float4(se.x, se.y, se.z, se.w);
    *(float4*)(ed + (size_t)gw*4) = make_float4(de.x, de.y, de.z, de.w);
  }
}

// ---------------- logits for layers 2,3 (bf16 input, one wave per row) ----------------
__global__ __launch_bounds__(256) void k_logits(const unsigned short* __restrict__ Xb,
    const float* __restrict__ was, const float* __restrict__ wad,
    float* __restrict__ es, float* __restrict__ ed){
  int gw = (blockIdx.x * blockDim.x + threadIdx.x) >> 6;
  int lane = threadIdx.x & 63;
  unsigned int u = *(const unsigned int*)(Xb + (size_t)gw*H_ + lane*2);
  float xlo = blo(u), xhi = bhi(u);
  int c = lane*2;
  const f32x4* w4 = (const f32x4*)was;
  const f32x4* d4 = (const f32x4*)wad;
  f32x4 se = xlo*w4[c] + xhi*w4[c+1];
  f32x4 de = xlo*d4[c] + xhi*d4[c+1];
  #pragma unroll
  for (int d = 1; d < 64; d <<= 1){
    se.x += __shfl_xor(se.x,d); se.y += __shfl_xor(se.y,d);
    se.z += __shfl_xor(se.z,d); se.w += __shfl_xor(se.w,d);
    de.x += __shfl_xor(de.x,d); de.y += __shfl_xor(de.y,d);
    de.z += __shfl_xor(de.z,d); de.w += __shfl_xor(de.w,d);
  }
  if (lane == 0){
    *(float4*)(es + (size_t)gw*4) = make_float4(se.x, se.y, se.z, se.w);
    *(float4*)(ed + (size_t)gw*4) = make_float4(de.x, de.y, de.z, de.w);
  }
}

// ---- h = x @ W: one block = 64 rows x all 512 cols; X staged once, Wt dbuf-looped.
// XCD affinity: graph g -> XCDs {2g, 2g+1} via idx%8 (dispatch round-robin).
__global__ __launch_bounds__(256) void k_gemm_mfma(const unsigned short* __restrict__ Xb,
    const unsigned short* __restrict__ Wt, unsigned short* __restrict__ Hb){
  __shared__ unsigned short xs[64*128];        // 16 KB
  __shared__ unsigned short ws[2][64*128];     // 32 KB double buffer
  int idx = blockIdx.x;
  int g = (idx & 7) >> 1;
  int j = ((idx >> 3) << 1) | (idx & 1);
  if (j >= 157) return;
  int rmax = N_ - j*64; if (rmax > 64) rmax = 64;   // rows valid (last block: 16)
  size_t row0 = (size_t)g*N_ + (size_t)j*64;
  int tid = threadIdx.x;
  int ch = tid & 15, r0 = tid >> 4;
  #pragma unroll
  for (int p = 0; p < 4; ++p){
    int r = r0 + p*16;
    int rr = (r < rmax) ? r : 0;
    int sc = ch ^ (r & 7);
    *(uint4*)(&xs[r*128 + sc*8]) = *(const uint4*)(Xb + (row0 + rr)*H_ + ch*8);
    *(uint4*)(&ws[0][r*128 + sc*8]) = *(const uint4*)(Wt + (size_t)r*H_ + ch*8);
  }
  __syncthreads();
  int w = tid >> 6, l = tid & 63;
  int lr = l & 15, q = l >> 4;
  int arow = w*16 + lr;
  bf16x8 afr[4];
  #pragma unroll
  for (int kf = 0; kf < 4; ++kf){
    int bch = kf*4 + q;
    afr[kf] = *(const bf16x8*)(&xs[arow*128 + (bch ^ (arow & 7))*8]);
  }
  #pragma unroll
  for (int cbk = 0; cbk < 8; ++cbk){
    int cur = cbk & 1;
    if (cbk < 7){
      #pragma unroll
      for (int p = 0; p < 4; ++p){
        int r = r0 + p*16;
        int sc = ch ^ (r & 7);
        *(uint4*)(&ws[cur^1][r*128 + sc*8]) =
            *(const uint4*)(Wt + (size_t)((cbk+1)*64 + r)*H_ + ch*8);
      }
    }
    f32x4 z = {0.f, 0.f, 0.f, 0.f};
    f32x4 acc[4] = {z, z, z, z};
    #pragma unroll
    for (int kf = 0; kf < 4; ++kf){
      int bch = kf*4 + q;
      #pragma unroll
      for (int cf = 0; cf < 4; ++cf){
        int brow = cf*16 + lr;
        bf16x8 bfr = *(const bf16x8*)(&ws[cur][brow*128 + (bch ^ (brow & 7))*8]);
        acc[cf] = __builtin_amdgcn_mfma_f32_16x16x32_bf16(afr[kf], bfr, acc[cf], 0, 0, 0);
      }
    }
    #pragma unroll
    for (int cf = 0; cf < 4; ++cf){
      #pragma unroll
      for (int rg = 0; rg < 4; ++rg){
        int rloc = w*16 + q*4 + rg;
        if (rloc < rmax){
          int col = cbk*64 + cf*16 + lr;
          Hb[(row0 + rloc)*HH_ + col] = f2b(acc[cf][rg]);
        }
      }
    }
    __syncthreads();
  }
}

// ---------------- aggregate: R2-verbatim + XCD-graph affinity swizzle ----------------
__global__ __launch_bounds__(256) void k_aggregate(const unsigned short* __restrict__ Hb,
    const float* __restrict__ es, const float* __restrict__ ed,
    const int* __restrict__ off, const int* __restrict__ csr,
    const float* __restrict__ bias, float* __restrict__ Y){
  int idx = blockIdx.x;
  int b = (idx & 7) >> 1;                       // graph -> XCD pair {2b, 2b+1}
  int j = ((idx >> 3) << 1) | (idx & 1);        // block within graph [0,2500)
  int lane = threadIdx.x & 63;
  int t = j*4 + (threadIdx.x >> 6);
  int gw = b*N_ + t;
  const float4 edv = *(const float4*)(ed + (size_t)gw*4);
  int start = off[b*(N_+1) + t];
  int deg = off[b*(N_+1) + t + 1] - start;
  const int* lst = csr + (size_t)b*E_ + start;

  // phase A: online softmax stats
  float m0=-1e30f, m1=-1e30f, m2=-1e30f, m3=-1e30f;
  float s0=0.f, s1=0.f, s2=0.f, s3=0.f;
  for (int i = lane; i <= deg; i += 64){
    int srcn = (i < deg) ? lst[i] : t;
    float4 ev = *(const float4*)(es + (size_t)(b*N_ + srcn)*4);
    float e0 = lrelu(ev.x + edv.x);
    float e1 = lrelu(ev.y + edv.y);
    float e2 = lrelu(ev.z + edv.z);
    float e3 = lrelu(ev.w + edv.w);
    float nm;
    nm = fmaxf(m0, e0); s0 = s0*__expf(m0-nm) + __expf(e0-nm); m0 = nm;
    nm = fmaxf(m1, e1); s1 = s1*__expf(m1-nm) + __expf(e1-nm); m1 = nm;
    nm = fmaxf(m2, e2); s2 = s2*__expf(m2-nm) + __expf(e2-nm); m2 = nm;
    nm = fmaxf(m3, e3); s3 = s3*__expf(m3-nm) + __expf(e3-nm); m3 = nm;
  }
  #pragma unroll
  for (int d = 1; d < 64; d <<= 1){
    float om, os, nm;
    om = __shfl_xor(m0, d); os = __shfl_xor(s0, d); nm = fmaxf(m0, om);
    s0 = s0*__expf(m0-nm) + os*__expf(om-nm); m0 = nm;
    om = __shfl_xor(m1, d); os = __shfl_xor(s1, d); nm = fmaxf(m1, om);
    s1 = s1*__expf(m1-nm) + os*__expf(om-nm); m1 = nm;
    om = __shfl_xor(m2, d); os = __shfl_xor(s2, d); nm = fmaxf(m2, om);
    s2 = s2*__expf(m2-nm) + os*__expf(om-nm); m2 = nm;
    om = __shfl_xor(m3, d); os = __shfl_xor(s3, d); nm = fmaxf(m3, om);
    s3 = s3*__expf(m3-nm) + os*__expf(om-nm); m3 = nm;
  }

  // phase B: weighted sum over bf16 h rows. lane -> (head = lane/16, 8 channels)
  int head = lane >> 4;
  float mh, sh, edh;
  if      (head == 0){ mh = m0; sh = s0; edh = edv.x; }
  else if (head == 1){ mh = m1; sh = s1; edh = edv.y; }
  else if (head == 2){ mh = m2; sh = s2; edh = edv.z; }
  else               { mh = m3; sh = s3; edh = edv.w; }
  float rh = 1.0f / sh;
  int cb = head*H_ + (lane & 15)*8;
  const unsigned short* hbase = Hb + (size_t)b*N_*HH_;
  const float* esb = es + (size_t)b*N_*4;
  float a[8] = {0.f,0.f,0.f,0.f,0.f,0.f,0.f,0.f};
  int total = deg + 1;    // + implicit self-loop
  int i = 0;
  for (; i + 1 < total; i += 2){
    int sA = lst[i];                       // i < deg guaranteed
    int sB = (i + 1 < deg) ? lst[i+1] : t;
    float eA = esb[(size_t)sA*4 + head];
    float eB = esb[(size_t)sB*4 + head];
    uint4 hA = *(const uint4*)(hbase + (size_t)sA*HH_ + cb);
    uint4 hB = *(const uint4*)(hbase + (size_t)sB*HH_ + cb);
    float aA = __expf(lrelu(eA + edh) - mh) * rh;
    float aB = __expf(lrelu(eB + edh) - mh) * rh;
    a[0] += aA*blo(hA.x); a[1] += aA*bhi(hA.x);
    a[2] += aA*blo(hA.y); a[3] += aA*bhi(hA.y);
    a[4] += aA*blo(hA.z); a[5] += aA*bhi(hA.z);
    a[6] += aA*blo(hA.w); a[7] += aA*bhi(hA.w);
    a[0] += aB*blo(hB.x); a[1] += aB*bhi(hB.x);
    a[2] += aB*blo(hB.y); a[3] += aB*bhi(hB.y);
    a[4] += aB*blo(hB.z); a[5] += aB*bhi(hB.z);
    a[6] += aB*blo(hB.w); a[7] += aB*bhi(hB.w);
  }
  if (i < total){
    int sA = (i < deg) ? lst[i] : t;
    float eA = esb[(size_t)sA*4 + head];
    uint4 hA = *(const uint4*)(hbase + (size_t)sA*HH_ + cb);
    float aA = __expf(lrelu(eA + edh) - mh) * rh;
    a[0] += aA*blo(hA.x); a[1] += aA*bhi(hA.x);
    a[2] += aA*blo(hA.y); a[3] += aA*bhi(hA.y);
    a[4] += aA*blo(hA.z); a[5] += aA*bhi(hA.z);
    a[6] += aA*blo(hA.w); a[7] += aA*bhi(hA.w);
  }
  // head mean
  #pragma unroll
  for (int d = 16; d < 64; d <<= 1)
    #pragma unroll
    for (int j2 = 0; j2 < 8; j2++) a[j2] += __shfl_xor(a[j2], d);
  if (lane < 16){
    int c = lane*8;
    float4 o0 = make_float4(0.25f*a[0]+bias[c+0], 0.25f*a[1]+bias[c+1],
                            0.25f*a[2]+bias[c+2], 0.25f*a[3]+bias[c+3]);
    float4 o1 = make_float4(0.25f*a[4]+bias[c+4], 0.25f*a[5]+bias[c+5],
                            0.25f*a[6]+bias[c+6], 0.25f*a[7]+bias[c+7]);
    *(float4*)(Y + (size_t)gw*H_ + c)     = o0;
    *(float4*)(Y + (size_t)gw*H_ + c + 4) = o1;
  }
}

// ---------------- LayerNorm + ReLU: read f32, write bf16 (next layer's input) ----------------
__global__ __launch_bounds__(256) void k_lnrelu(const float* __restrict__ Y,
    const float* __restrict__ g, const float* __restrict__ bb, unsigned short* __restrict__ Xb){
  int gw = (blockIdx.x*blockDim.x + threadIdx.x) >> 6;
  int lane = threadIdx.x & 63;
  float2 v = *(const float2*)(Y + (size_t)gw*H_ + lane*2);
  float sum = v.x + v.y;
  #pragma unroll
  for (int d = 1; d < 64; d <<= 1) sum += __shfl_xor(sum, d);
  float mu = sum * (1.f/H_);
  float dx = v.x - mu, dy = v.y - mu;
  float vs = dx*dx + dy*dy;
  #pragma unroll
  for (int d = 1; d < 64; d <<= 1) vs += __shfl_xor(vs, d);
  float inv = rsqrtf(vs*(1.f/H_) + 1e-5f);
  float2 gv = *(const float2*)(g + lane*2);
  float2 bv = *(const float2*)(bb + lane*2);
  float ox = fmaxf(dx*inv*gv.x + bv.x, 0.f);
  float oy = fmaxf(dy*inv*gv.y + bv.y, 0.f);
  unsigned int o = ((unsigned int)f2b(oy) << 16) | (unsigned int)f2b(ox);
  *(unsigned int*)(Xb + (size_t)gw*H_ + lane*2) = o;
}

extern "C" void kernel_launch(void* const* d_in, const int* in_sizes, int n_in,
                              void* d_out, int out_size, void* d_ws, size_t ws_size,
                              hipStream_t stream){
  const float* x0   = (const float*)d_in[0];
  const int*   srcI = (const int*)d_in[1];
  const int*   tgtI = (const int*)d_in[2];
  const float* Wl[3]  = {(const float*)d_in[3], (const float*)d_in[7],  (const float*)d_in[11]};
  const float* asl[3] = {(const float*)d_in[4], (const float*)d_in[8],  (const float*)d_in[12]};
  const float* adl[3] = {(const float*)d_in[5], (const float*)d_in[9],  (const float*)d_in[13]};
  const float* bl[3]  = {(const float*)d_in[6], (const float*)d_in[10], (const float*)d_in[14]};
  const float* lng[2] = {(const float*)d_in[15], (const float*)d_in[17]};
  const float* lnb[2] = {(const float*)d_in[16], (const float*)d_in[18]};

  char* p = (char*)d_ws;
  auto carve = [&](size_t bytes) -> void* {
    void* r = (void*)p; p += (bytes + 255) & ~(size_t)255; return r;
  };
  int*   off    = (int*)carve((size_t)B_*(N_+1)*4);
  int*   cnt    = (int*)carve((size_t)B_*N_*4);
  int*   cursor = (int*)carve((size_t)B_*N_*4);
  int*   csr    = (int*)carve((size_t)B_*E_*4);
  float* es     = (float*)carve((size_t)NROWS*4*4);
  float* ed     = (float*)carve((size_t)NROWS*4*4);
  float* wasA   = (float*)carve((size_t)3*HH_*4);
  float* wadA   = (float*)carve((size_t)3*HH_*4);
  unsigned short* wtA  = (unsigned short*)carve((size_t)3*HH_*H_*2);
  unsigned short* hbuf = (unsigned short*)carve((size_t)NROWS*HH_*2);
  unsigned short* xbf  = (unsigned short*)carve((size_t)NROWS*H_*2);
  float* tbuf   = (float*)carve((size_t)NROWS*H_*4);

  hipMemsetAsync(cnt, 0, (size_t)B_*N_*4, stream);
  k_count  <<<dim3(E_/256, B_), 256, 0, stream>>>(tgtI, cnt);
  k_scan   <<<B_, 1024, 0, stream>>>(cnt, off, cursor);
  k_scatter<<<dim3(E_/256, B_), 256, 0, stream>>>(srcI, tgtI, cursor, csr);
  k_prep   <<<dim3(258, 3), 256, 0, stream>>>(Wl[0], Wl[1], Wl[2],
                                              asl[0], asl[1], asl[2],
                                              adl[0], adl[1], adl[2],
                                              wasA, wadA, wtA);
  k_cast_logits<<<NROWS/4, 256, 0, stream>>>(x0, wasA, wadA, xbf, es, ed);

  for (int l = 0; l < 3; ++l){
    k_gemm_mfma<<<632, 256, 0, stream>>>(xbf, wtA + (size_t)l*HH_*H_, hbuf);
    float* yout = (l == 2) ? (float*)d_out : tbuf;
    k_aggregate<<<NROWS/4, 256, 0, stream>>>(hbuf, es, ed, off, csr, bl[l], yout);
    if (l < 2){
      k_lnrelu<<<NROWS/4, 256, 0, stream>>>(tbuf, lng[l], lnb[l], xbf);
      k_logits<<<NROWS/4, 256, 0, stream>>>(xbf, wasA + (size_t)(l+1)*HH_, wadA + (size_t)(l+1)*HH_, es, ed);
    }
  }
}

// Round 12
// 448.703 us; speedup vs baseline: 1.2102x; 1.0169x over previous
//
#include <hip/hip_runtime.h>
#include <hip/hip_bf16.h>
#include <cstdint>
#include <cstddef>

#define B_ 4
#define N_ 10000
#define E_ 160000
#define H_ 128
#define HEADS_ 4
#define HH_ 512
#define NROWS (B_*N_)

typedef __attribute__((ext_vector_type(8))) short bf16x8;
typedef __attribute__((ext_vector_type(4))) float f32x4;
typedef __attribute__((ext_vector_type(2))) float f32x2;

__device__ __forceinline__ float lrelu(float x){ return x > 0.f ? x : 0.2f*x; }
__device__ __forceinline__ unsigned short f2b(float f){
  unsigned int u = __builtin_bit_cast(unsigned int, f);
  unsigned int r = (u + 0x7fffu + ((u >> 16) & 1u)) >> 16;
  return (unsigned short)r;
}
__device__ __forceinline__ float blo(unsigned int u){ return __builtin_bit_cast(float, u << 16); }
__device__ __forceinline__ float bhi(unsigned int u){ return __builtin_bit_cast(float, u & 0xffff0000u); }

__device__ __forceinline__ void acc_row(f32x2* ac, float al, uint4 h){
  f32x2 v = {al, al};
  ac[0] += v * (f32x2){blo(h.x), bhi(h.x)};
  ac[1] += v * (f32x2){blo(h.y), bhi(h.y)};
  ac[2] += v * (f32x2){blo(h.z), bhi(h.z)};
  ac[3] += v * (f32x2){blo(h.w), bhi(h.w)};
}

// ---------------- CSR build ----------------
__global__ void k_count(const int* __restrict__ tgt, int* __restrict__ cnt){
  int e = blockIdx.x*blockDim.x + threadIdx.x;
  int b = blockIdx.y;
  int t = tgt[(size_t)b*E_ + e];
  atomicAdd(&cnt[b*N_ + t], 1);
}

__global__ void k_scan(const int* __restrict__ cnt, int* __restrict__ off, int* __restrict__ cursor){
  int b = blockIdx.x;
  __shared__ int wsum[16];
  __shared__ int carry_s;
  int lane = threadIdx.x & 63, wid = threadIdx.x >> 6;
  if (threadIdx.x == 0){ carry_s = 0; off[b*(N_+1)] = 0; }
  __syncthreads();
  for (int base = 0; base < N_; base += 1024){
    int i = base + threadIdx.x;
    int v = (i < N_) ? cnt[b*N_ + i] : 0;
    int x = v;
    #pragma unroll
    for (int d = 1; d < 64; d <<= 1){
      int y = __shfl_up(x, d);
      if (lane >= d) x += y;
    }
    if (lane == 63) wsum[wid] = x;
    __syncthreads();
    if (wid == 0 && lane < 16){
      int w = wsum[lane];
      #pragma unroll
      for (int d = 1; d < 16; d <<= 1){
        int y = __shfl_up(w, d, 16);
        if (lane >= d) w += y;
      }
      wsum[lane] = w;
    }
    __syncthreads();
    int excl = (wid ? wsum[wid-1] : 0) + carry_s;
    if (i < N_){
      int inc = x + excl;
      off[b*(N_+1) + i + 1] = inc;
      cursor[b*N_ + i] = inc - v;
    }
    __syncthreads();
    if (threadIdx.x == 0) carry_s += wsum[15];
    __syncthreads();
  }
}

__global__ void k_scatter(const int* __restrict__ src, const int* __restrict__ tgt,
                          int* __restrict__ cursor, int* __restrict__ csr){
  int e = blockIdx.x*blockDim.x + threadIdx.x;
  int b = blockIdx.y;
  int t = tgt[(size_t)b*E_ + e];
  int pos = atomicAdd(&cursor[b*N_ + t], 1);
  csr[(size_t)b*E_ + pos] = src[(size_t)b*E_ + e];
}

// ---------------- prep: Wa tables + W transpose/cast, all 3 layers ----------------
__global__ void k_prep(const float* __restrict__ W0, const float* __restrict__ W1, const float* __restrict__ W2,
                       const float* __restrict__ as0, const float* __restrict__ as1, const float* __restrict__ as2,
                       const float* __restrict__ ad0, const float* __restrict__ ad1, const float* __restrict__ ad2,
                       float* __restrict__ wasA, float* __restrict__ wadA, unsigned short* __restrict__ wtA){
  int l = blockIdx.y;
  const float* W   = (l==0)?W0:(l==1)?W1:W2;
  const float* asp = (l==0)?as0:(l==1)?as1:as2;
  const float* adp = (l==0)?ad0:(l==1)?ad1:ad2;
  if (blockIdx.x < 256){
    int i = blockIdx.x*256 + threadIdx.x;     // i = c*H_ + k
    int c = i >> 7, k = i & 127;
    wtA[(size_t)l*HH_*H_ + i] = f2b(W[(size_t)k*HH_ + c]);
  } else {
    int j = (blockIdx.x - 256)*256 + threadIdx.x;   // j = k*4 + h
    if (j < H_*HEADS_){
      int k = j >> 2, h = j & 3;
      const float* wrow = W + (size_t)k*HH_ + h*H_;
      const float* asr = asp + h*H_;
      const float* adr = adp + h*H_;
      float ss = 0.f, sd = 0.f;
      for (int c = 0; c < H_; ++c){ float w = wrow[c]; ss += w*asr[c]; sd += w*adr[c]; }
      wasA[l*HH_ + j] = ss; wadA[l*HH_ + j] = sd;
    }
  }
}

// ---------------- layer-1: cast x->bf16 + logits (one wave per row) ----------------
__global__ __launch_bounds__(256) void k_cast_logits(const float* __restrict__ X,
    const float* __restrict__ was, const float* __restrict__ wad,
    unsigned short* __restrict__ Xb, float* __restrict__ es, float* __restrict__ ed){
  int gw = (blockIdx.x*blockDim.x + threadIdx.x) >> 6;
  int lane = threadIdx.x & 63;
  float2 v = *(const float2*)(X + (size_t)gw*H_ + lane*2);
  unsigned int o = ((unsigned int)f2b(v.y) << 16) | (unsigned int)f2b(v.x);
  *(unsigned int*)(Xb + (size_t)gw*H_ + lane*2) = o;
  int c = lane*2;
  const f32x4* w4 = (const f32x4*)was;
  const f32x4* d4 = (const f32x4*)wad;
  f32x4 se = v.x*w4[c] + v.y*w4[c+1];
  f32x4 de = v.x*d4[c] + v.y*d4[c+1];
  #pragma unroll
  for (int d = 1; d < 64; d <<= 1){
    se.x += __shfl_xor(se.x,d); se.y += __shfl_xor(se.y,d);
    se.z += __shfl_xor(se.z,d); se.w += __shfl_xor(se.w,d);
    de.x += __shfl_xor(de.x,d); de.y += __shfl_xor(de.y,d);
    de.z += __shfl_xor(de.z,d); de.w += __shfl_xor(de.w,d);
  }
  if (lane == 0){
    *(float4*)(es + (size_t)gw*4) = make_float4(se.x, se.y, se.z, se.w);
    *(float4*)(ed + (size_t)gw*4) = make_float4(de.x, de.y, de.z, de.w);
  }
}

// ---- h = x @ W: one block = 64 rows x all 512 cols; X staged once, Wt dbuf-looped. ----
__global__ __launch_bounds__(256) void k_gemm_mfma(const unsigned short* __restrict__ Xb,
    const unsigned short* __restrict__ Wt, unsigned short* __restrict__ Hb){
  __shared__ unsigned short xs[64*128];        // 16 KB
  __shared__ unsigned short ws[2][64*128];     // 32 KB double buffer
  int idx = blockIdx.x;
  int g = (idx & 7) >> 1;
  int j = ((idx >> 3) << 1) | (idx & 1);
  if (j >= 157) return;
  int rmax = N_ - j*64; if (rmax > 64) rmax = 64;
  size_t row0 = (size_t)g*N_ + (size_t)j*64;
  int tid = threadIdx.x;
  int ch = tid & 15, r0 = tid >> 4;
  #pragma unroll
  for (int p = 0; p < 4; ++p){
    int r = r0 + p*16;
    int rr = (r < rmax) ? r : 0;
    int sc = ch ^ (r & 7);
    *(uint4*)(&xs[r*128 + sc*8]) = *(const uint4*)(Xb + (row0 + rr)*H_ + ch*8);
    *(uint4*)(&ws[0][r*128 + sc*8]) = *(const uint4*)(Wt + (size_t)r*H_ + ch*8);
  }
  __syncthreads();
  int w = tid >> 6, l = tid & 63;
  int lr = l & 15, q = l >> 4;
  int arow = w*16 + lr;
  bf16x8 afr[4];
  #pragma unroll
  for (int kf = 0; kf < 4; ++kf){
    int bch = kf*4 + q;
    afr[kf] = *(const bf16x8*)(&xs[arow*128 + (bch ^ (arow & 7))*8]);
  }
  #pragma unroll
  for (int cbk = 0; cbk < 8; ++cbk){
    int cur = cbk & 1;
    if (cbk < 7){
      #pragma unroll
      for (int p = 0; p < 4; ++p){
        int r = r0 + p*16;
        int sc = ch ^ (r & 7);
        *(uint4*)(&ws[cur^1][r*128 + sc*8]) =
            *(const uint4*)(Wt + (size_t)((cbk+1)*64 + r)*H_ + ch*8);
      }
    }
    f32x4 z = {0.f, 0.f, 0.f, 0.f};
    f32x4 acc[4] = {z, z, z, z};
    #pragma unroll
    for (int kf = 0; kf < 4; ++kf){
      int bch = kf*4 + q;
      #pragma unroll
      for (int cf = 0; cf < 4; ++cf){
        int brow = cf*16 + lr;
        bf16x8 bfr = *(const bf16x8*)(&ws[cur][brow*128 + (bch ^ (brow & 7))*8]);
        acc[cf] = __builtin_amdgcn_mfma_f32_16x16x32_bf16(afr[kf], bfr, acc[cf], 0, 0, 0);
      }
    }
    #pragma unroll
    for (int cf = 0; cf < 4; ++cf){
      #pragma unroll
      for (int rg = 0; rg < 4; ++rg){
        int rloc = w*16 + q*4 + rg;
        if (rloc < rmax){
          int col = cbk*64 + cf*16 + lr;
          Hb[(row0 + rloc)*HH_ + col] = f2b(acc[cf][rg]);
        }
      }
    }
    __syncthreads();
  }
}

// ---------------- aggregate: long phase A + pk-math phase B + XCD swizzle ----------------
__global__ __launch_bounds__(256) void k_aggregate(const unsigned short* __restrict__ Hb,
    const float* __restrict__ es, const float* __restrict__ ed,
    const int* __restrict__ off, const int* __restrict__ csr,
    const float* __restrict__ bias, float* __restrict__ Y){
  int idx = blockIdx.x;
  int b = (idx & 7) >> 1;                       // graph -> XCD pair {2b, 2b+1}
  int j = ((idx >> 3) << 1) | (idx & 1);        // block within graph [0,2500)
  int lane = threadIdx.x & 63;
  int t = j*4 + (threadIdx.x >> 6);
  int gw = b*N_ + t;
  const float4 edv = *(const float4*)(ed + (size_t)gw*4);
  int start = off[b*(N_+1) + t];
  int deg = off[b*(N_+1) + t + 1] - start;
  const int* lst = csr + (size_t)b*E_ + start;

  // phase A: online softmax stats (long form — staggers waves, hides phase-B ramp)
  float m0=-1e30f, m1=-1e30f, m2=-1e30f, m3=-1e30f;
  float s0=0.f, s1=0.f, s2=0.f, s3=0.f;
  for (int i = lane; i <= deg; i += 64){
    int srcn = (i < deg) ? lst[i] : t;
    float4 ev = *(const float4*)(es + (size_t)(b*N_ + srcn)*4);
    float e0 = lrelu(ev.x + edv.x);
    float e1 = lrelu(ev.y + edv.y);
    float e2 = lrelu(ev.z + edv.z);
    float e3 = lrelu(ev.w + edv.w);
    float nm;
    nm = fmaxf(m0, e0); s0 = s0*__expf(m0-nm) + __expf(e0-nm); m0 = nm;
    nm = fmaxf(m1, e1); s1 = s1*__expf(m1-nm) + __expf(e1-nm); m1 = nm;
    nm = fmaxf(m2, e2); s2 = s2*__expf(m2-nm) + __expf(e2-nm); m2 = nm;
    nm = fmaxf(m3, e3); s3 = s3*__expf(m3-nm) + __expf(e3-nm); m3 = nm;
  }
  #pragma unroll
  for (int d = 1; d < 64; d <<= 1){
    float om, os, nm;
    om = __shfl_xor(m0, d); os = __shfl_xor(s0, d); nm = fmaxf(m0, om);
    s0 = s0*__expf(m0-nm) + os*__expf(om-nm); m0 = nm;
    om = __shfl_xor(m1, d); os = __shfl_xor(s1, d); nm = fmaxf(m1, om);
    s1 = s1*__expf(m1-nm) + os*__expf(om-nm); m1 = nm;
    om = __shfl_xor(m2, d); os = __shfl_xor(s2, d); nm = fmaxf(m2, om);
    s2 = s2*__expf(m2-nm) + os*__expf(om-nm); m2 = nm;
    om = __shfl_xor(m3, d); os = __shfl_xor(s3, d); nm = fmaxf(m3, om);
    s3 = s3*__expf(m3-nm) + os*__expf(om-nm); m3 = nm;
  }

  // phase B: weighted sum; alpha = exp(e - Lh), Lh = m + log(S)
  int head = lane >> 4;
  float mh, sh, edh;
  if      (head == 0){ mh = m0; sh = s0; edh = edv.x; }
  else if (head == 1){ mh = m1; sh = s1; edh = edv.y; }
  else if (head == 2){ mh = m2; sh = s2; edh = edv.z; }
  else               { mh = m3; sh = s3; edh = edv.w; }
  float Lh = mh + __logf(sh);
  int cb = head*H_ + (lane & 15)*8;
  const unsigned short* hbase = Hb + (size_t)b*N_*HH_;
  const float* esb = es + (size_t)b*N_*4;
  f32x2 zz = {0.f, 0.f};
  f32x2 ac[4] = {zz, zz, zz, zz};
  int total = deg + 1;    // + implicit self-loop
  int i = 0;
  for (; i + 1 < total; i += 2){
    int sA = lst[i];                       // i < deg guaranteed
    int sB = (i + 1 < deg) ? lst[i+1] : t;
    float eA = esb[(size_t)sA*4 + head];
    float eB = esb[(size_t)sB*4 + head];
    uint4 hA = *(const uint4*)(hbase + (size_t)sA*HH_ + cb);
    uint4 hB = *(const uint4*)(hbase + (size_t)sB*HH_ + cb);
    float aA = __expf(lrelu(eA + edh) - Lh);
    float aB = __expf(lrelu(eB + edh) - Lh);
    acc_row(ac, aA, hA);
    acc_row(ac, aB, hB);
  }
  if (i < total){
    int sA = (i < deg) ? lst[i] : t;
    float eA = esb[(size_t)sA*4 + head];
    uint4 hA = *(const uint4*)(hbase + (size_t)sA*HH_ + cb);
    float aA = __expf(lrelu(eA + edh) - Lh);
    acc_row(ac, aA, hA);
  }
  // head mean
  float a[8] = {ac[0].x, ac[0].y, ac[1].x, ac[1].y, ac[2].x, ac[2].y, ac[3].x, ac[3].y};
  #pragma unroll
  for (int d = 16; d < 64; d <<= 1)
    #pragma unroll
    for (int j2 = 0; j2 < 8; j2++) a[j2] += __shfl_xor(a[j2], d);
  if (lane < 16){
    int c = lane*8;
    float4 o0 = make_float4(0.25f*a[0]+bias[c+0], 0.25f*a[1]+bias[c+1],
                            0.25f*a[2]+bias[c+2], 0.25f*a[3]+bias[c+3]);
    float4 o1 = make_float4(0.25f*a[4]+bias[c+4], 0.25f*a[5]+bias[c+5],
                            0.25f*a[6]+bias[c+6], 0.25f*a[7]+bias[c+7]);
    *(float4*)(Y + (size_t)gw*H_ + c)     = o0;
    *(float4*)(Y + (size_t)gw*H_ + c + 4) = o1;
  }
}

// ---------------- fused LayerNorm+ReLU + next-layer logits (one wave per row) ----------------
__global__ __launch_bounds__(256) void k_lnrelu_logits(const float* __restrict__ Y,
    const float* __restrict__ g, const float* __restrict__ bb,
    const float* __restrict__ was, const float* __restrict__ wad,
    unsigned short* __restrict__ Xb, float* __restrict__ es, float* __restrict__ ed){
  int gw = (blockIdx.x*blockDim.x + threadIdx.x) >> 6;
  int lane = threadIdx.x & 63;
  float2 v = *(const float2*)(Y + (size_t)gw*H_ + lane*2);
  float sum = v.x + v.y;
  #pragma unroll
  for (int d = 1; d < 64; d <<= 1) sum += __shfl_xor(sum, d);
  float mu = sum * (1.f/H_);
  float dx = v.x - mu, dy = v.y - mu;
  float vs = dx*dx + dy*dy;
  #pragma unroll
  for (int d = 1; d < 64; d <<= 1) vs += __shfl_xor(vs, d);
  float inv = rsqrtf(vs*(1.f/H_) + 1e-5f);
  float2 gv = *(const float2*)(g + lane*2);
  float2 bv = *(const float2*)(bb + lane*2);
  float ox = fmaxf(dx*inv*gv.x + bv.x, 0.f);
  float oy = fmaxf(dy*inv*gv.y + bv.y, 0.f);
  unsigned int o = ((unsigned int)f2b(oy) << 16) | (unsigned int)f2b(ox);
  *(unsigned int*)(Xb + (size_t)gw*H_ + lane*2) = o;
  // logits for next layer from in-register row
  int c = lane*2;
  const f32x4* w4 = (const f32x4*)was;
  const f32x4* d4 = (const f32x4*)wad;
  f32x4 se = ox*w4[c] + oy*w4[c+1];
  f32x4 de = ox*d4[c] + oy*d4[c+1];
  #pragma unroll
  for (int d = 1; d < 64; d <<= 1){
    se.x += __shfl_xor(se.x,d); se.y += __shfl_xor(se.y,d);
    se.z += __shfl_xor(se.z,d); se.w += __shfl_xor(se.w,d);
    de.x += __shfl_xor(de.x,d); de.y += __shfl_xor(de.y,d);
    de.z += __shfl_xor(de.z,d); de.w += __shfl_xor(de.w,d);
  }
  if (lane == 0){
    *(float4*)(es + (size_t)gw*4) = make_float4(se.x, se.y, se.z, se.w);
    *(float4*)(ed + (size_t)gw*4) = make_float4(de.x, de.y, de.z, de.w);
  }
}

extern "C" void kernel_launch(void* const* d_in, const int* in_sizes, int n_in,
                              void* d_out, int out_size, void* d_ws, size_t ws_size,
                              hipStream_t stream){
  const float* x0   = (const float*)d_in[0];
  const int*   srcI = (const int*)d_in[1];
  const int*   tgtI = (const int*)d_in[2];
  const float* Wl[3]  = {(const float*)d_in[3], (const float*)d_in[7],  (const float*)d_in[11]};
  const float* asl[3] = {(const float*)d_in[4], (const float*)d_in[8],  (const float*)d_in[12]};
  const float* adl[3] = {(const float*)d_in[5], (const float*)d_in[9],  (const float*)d_in[13]};
  const float* bl[3]  = {(const float*)d_in[6], (const float*)d_in[10], (const float*)d_in[14]};
  const float* lng[2] = {(const float*)d_in[15], (const float*)d_in[17]};
  const float* lnb[2] = {(const float*)d_in[16], (const float*)d_in[18]};

  char* p = (char*)d_ws;
  auto carve = [&](size_t bytes) -> void* {
    void* r = (void*)p; p += (bytes + 255) & ~(size_t)255; return r;
  };
  int*   off    = (int*)carve((size_t)B_*(N_+1)*4);
  int*   cnt    = (int*)carve((size_t)B_*N_*4);
  int*   cursor = (int*)carve((size_t)B_*N_*4);
  int*   csr    = (int*)carve((size_t)B_*E_*4);
  float* es     = (float*)carve((size_t)NROWS*4*4);
  float* ed     = (float*)carve((size_t)NROWS*4*4);
  float* wasA   = (float*)carve((size_t)3*HH_*4);
  float* wadA   = (float*)carve((size_t)3*HH_*4);
  unsigned short* wtA  = (unsigned short*)carve((size_t)3*HH_*H_*2);
  unsigned short* hbuf = (unsigned short*)carve((size_t)NROWS*HH_*2);
  unsigned short* xbf  = (unsigned short*)carve((size_t)NROWS*H_*2);
  float* tbuf   = (float*)carve((size_t)NROWS*H_*4);

  hipMemsetAsync(cnt, 0, (size_t)B_*N_*4, stream);
  k_count  <<<dim3(E_/256, B_), 256, 0, stream>>>(tgtI, cnt);
  k_scan   <<<B_, 1024, 0, stream>>>(cnt, off, cursor);
  k_scatter<<<dim3(E_/256, B_), 256, 0, stream>>>(srcI, tgtI, cursor, csr);
  k_prep   <<<dim3(258, 3), 256, 0, stream>>>(Wl[0], Wl[1], Wl[2],
                                              asl[0], asl[1], asl[2],
                                              adl[0], adl[1], adl[2],
                                              wasA, wadA, wtA);
  k_cast_logits<<<NROWS/4, 256, 0, stream>>>(x0, wasA, wadA, xbf, es, ed);

  for (int l = 0; l < 3; ++l){
    k_gemm_mfma<<<632, 256, 0, stream>>>(xbf, wtA + (size_t)l*HH_*H_, hbuf);
    float* yout = (l == 2) ? (float*)d_out : tbuf;
    k_aggregate<<<NROWS/4, 256, 0, stream>>>(hbuf, es, ed, off, csr, bl[l], yout);
    if (l < 2){
      k_lnrelu_logits<<<NROWS/4, 256, 0, stream>>>(tbuf, lng[l], lnb[l],
          wasA + (size_t)(l+1)*HH_, wadA + (size_t)(l+1)*HH_, xbf, es, ed);
    }
  }
}